// Round 7
// baseline (679.266 us; speedup 1.0000x reference)
//
#include <hip/hip_runtime.h>
#include <stdint.h>
#include <stddef.h>

#define Bsz   2
#define Ssz   2048
#define HIDsz 4096
#define Hsz   32
#define KVsz  8
#define Dsz   128
#define NQKV  6144                     // (H+2KV)*D
// Q scale = 1/sqrt(128) * log2(e): softmax computed base-2 (exp2 is the HW op)
#define QSCALE 0.12752057463f
#define L2_1E4_64 0.20762050595f       // log2(10000)/64

typedef __bf16 bf16x8 __attribute__((ext_vector_type(8)));
typedef float  f32x4  __attribute__((ext_vector_type(4)));
typedef float  f32x16 __attribute__((ext_vector_type(16)));
typedef unsigned short u16;
typedef u16 u16x4 __attribute__((ext_vector_type(4)));
typedef u16 u16x8 __attribute__((ext_vector_type(8)));
typedef uint32_t u32x4 __attribute__((ext_vector_type(4)));

__device__ __forceinline__ u16 f2bf(float f) {
  uint32_t u = __builtin_bit_cast(uint32_t, f);
  u = (u + 0x7FFFu + ((u >> 16) & 1u)) >> 16;   // RNE
  return (u16)u;
}
__device__ __forceinline__ u16 f2bf_fast(float f) {  // round-half-up, 2 VALU
  uint32_t u = __builtin_bit_cast(uint32_t, f);
  return (u16)((u + 0x8000u) >> 16);
}
__device__ __forceinline__ float bf2f(u16 h) {
  return __builtin_bit_cast(float, (uint32_t)h << 16);
}
__device__ __forceinline__ uint32_t packbf2(float lo, float hi_) {
  return (uint32_t)f2bf_fast(lo) | ((uint32_t)f2bf_fast(hi_) << 16);
}

// global -> LDS async copy, 16B per lane; LDS dest = wave-uniform base + lane*16
#define GLDS(gp, lp) __builtin_amdgcn_global_load_lds( \
    (__attribute__((address_space(1))) void*)(void*)(gp), \
    (__attribute__((address_space(3))) void*)(lp), 16, 0, 0)

// ---------------- fused fp32->bf16 conversion (one launch, 3 tensors) -------
#define N4_HS  ((Bsz * Ssz * HIDsz) / 4)
#define N4_WQ  ((NQKV * HIDsz) / 4)
#define N4_WO  ((HIDsz * HIDsz) / 4)
__global__ __launch_bounds__(256) void k_cvt3(const float* __restrict__ hs,
                                              const float* __restrict__ wqkv,
                                              const float* __restrict__ wo,
                                              u16* __restrict__ xbf,
                                              u16* __restrict__ wqbf,
                                              u16* __restrict__ wobf) {
  int i = blockIdx.x * 256 + threadIdx.x;
  const float* src; u16* dst; int off;
  if (i < N4_HS)                   { src = hs;   dst = xbf;  off = i; }
  else if (i < N4_HS + N4_WQ)      { src = wqkv; dst = wqbf; off = i - N4_HS; }
  else if (i < N4_HS + N4_WQ + N4_WO) { src = wo; dst = wobf; off = i - N4_HS - N4_WQ; }
  else return;
  float4 v = ((const float4*)src)[off];
  u16x4 o;
  o.x = f2bf(v.x); o.y = f2bf(v.y); o.z = f2bf(v.z); o.w = f2bf(v.w);
  ((u16x4*)dst)[off] = o;
}

// RoPE on q,k with inline sincos; q scaled by QSCALE (incl. log2e for exp2
// softmax); writes Qr[b][h][s][d], Kr[b][kvh][s][d]
__global__ __launch_bounds__(256) void k_rope(const u16* __restrict__ qkv,
                                              const int* __restrict__ pos,
                                              u16* __restrict__ Qr, u16* __restrict__ Kr) {
  int idx = blockIdx.x * 256 + threadIdx.x;       // B*S*(H+KV)*64
  if (idx >= Bsz * Ssz * (Hsz + KVsz) * 64) return;
  int j = idx & 63;
  int head = (idx >> 6) % (Hsz + KVsz);
  int bs = idx / (64 * (Hsz + KVsz));
  const u16* row = qkv + (size_t)bs * NQKV + head * Dsz;
  float x1 = bf2f(row[j]), x2 = bf2f(row[j + 64]);
  float p = (float)pos[bs];
  float ang = p * exp2f(-(float)j * L2_1E4_64);   // p * 10000^(-j/64)
  float s, c;
  __sincosf(ang, &s, &c);
  float o1 = x1 * c - x2 * s;
  float o2 = x2 * c + x1 * s;
  int b = bs / Ssz, sidx = bs % Ssz;
  if (head < Hsz) {
    u16* o = Qr + ((size_t)(b * Hsz + head) * Ssz + sidx) * Dsz;
    o[j] = f2bf(o1 * QSCALE); o[j + 64] = f2bf(o2 * QSCALE);
  } else {
    int kvh = head - Hsz;
    u16* o = Kr + ((size_t)(b * KVsz + kvh) * Ssz + sidx) * Dsz;
    o[j] = f2bf(o1); o[j + 64] = f2bf(o2);
  }
}

// V transpose, LDS-tiled: Vt[b][kvh][d][s] = qkv[b,s, (H+KV)*D + kvh*D + d]
__global__ __launch_bounds__(256) void k_vtrans(const u16* __restrict__ qkv,
                                                u16* __restrict__ Vt) {
  __shared__ __align__(16) u16 Tl[64 * 72];
  const int tid = threadIdx.x;
  const int bk = blockIdx.y;                      // b*KV + kvh
  const int s0 = (blockIdx.x >> 1) * 64;
  const int d0 = (blockIdx.x & 1) * 64;
  const int b = bk >> 3, kvh = bk & 7;
  const u16* src = qkv + (size_t)(b * Ssz + s0) * NQKV + (Hsz + KVsz) * Dsz + kvh * Dsz + d0;
#pragma unroll
  for (int p = 0; p < 2; ++p) {
    int cid = p * 256 + tid;
    int r = cid >> 3, co = cid & 7;
    int chunk = co ^ ((r >> 3) & 7);
    *(u16x8*)((char*)Tl + r * 144 + chunk * 16) =
        *(const u16x8*)(src + (size_t)r * NQKV + co * 8);
  }
  __syncthreads();
#pragma unroll
  for (int p = 0; p < 2; ++p) {
    int cid = p * 256 + tid;
    int dr = cid >> 3, c = cid & 7;
    u16x8 v;
#pragma unroll
    for (int j = 0; j < 8; ++j) {
      int s = 8 * c + j;
      v[j] = *(const u16*)((char*)Tl + s * 144 + (((dr >> 3) ^ c) * 16) + (dr & 7) * 2);
    }
    *(u16x8*)(Vt + ((size_t)bk * Dsz + d0 + dr) * Ssz + s0 + 8 * c) = v;
  }
}

// ============ 256x256 8-phase GEMM: C[M][N] = A[M][K] * B[N][K]^T ============
// v4: tile order flipped to column-major (bm = swz % MBt) so each XCD's
// contiguous chunk = column strips; concurrent blocks share 2 B-panels
// (4MB = L2-fits, 16-way) instead of streaming 48MB of B per XCD round.
// Sync structure = r5/r6 (single barrier/phase, A-frag prefetch, vmcnt(6)).

#define BARX do { asm volatile("" ::: "memory"); __builtin_amdgcn_s_barrier(); \
                  asm volatile("" ::: "memory"); } while (0)
#define VM6  asm volatile("s_waitcnt vmcnt(6)" ::: "memory")
#define VM0  asm volatile("s_waitcnt vmcnt(0)" ::: "memory")

#define LOADA4(P_, Q_, F_) do {                                               \
    afr[F_][0] = LDA(P_, Q_, 0, 0); afr[F_][1] = LDA(P_, Q_, 0, 1);           \
    afr[F_][2] = LDA(P_, Q_, 1, 0); afr[F_][3] = LDA(P_, Q_, 1, 1);           \
  } while (0)

#define LOADB8(P_) do {                                                       \
    _Pragma("unroll") for (int nf = 0; nf < 4; ++nf) {                        \
      bfr[nf][0] = LDB(P_, nf, 0); bfr[nf][1] = LDB(P_, nf, 1); }             \
  } while (0)

#define MMA16(Q_, F_) do {                                                    \
    __builtin_amdgcn_s_setprio(1);                                            \
    _Pragma("unroll") for (int nf = 0; nf < 4; ++nf) {                        \
      acc[(Q_)*2][nf]   = __builtin_amdgcn_mfma_f32_16x16x32_bf16(afr[F_][0], bfr[nf][0], acc[(Q_)*2][nf],   0,0,0); \
      acc[(Q_)*2+1][nf] = __builtin_amdgcn_mfma_f32_16x16x32_bf16(afr[F_][2], bfr[nf][0], acc[(Q_)*2+1][nf], 0,0,0); \
    }                                                                         \
    _Pragma("unroll") for (int nf = 0; nf < 4; ++nf) {                        \
      acc[(Q_)*2][nf]   = __builtin_amdgcn_mfma_f32_16x16x32_bf16(afr[F_][1], bfr[nf][1], acc[(Q_)*2][nf],   0,0,0); \
      acc[(Q_)*2+1][nf] = __builtin_amdgcn_mfma_f32_16x16x32_bf16(afr[F_][3], bfr[nf][1], acc[(Q_)*2+1][nf], 0,0,0); \
    }                                                                         \
    __builtin_amdgcn_s_setprio(0);                                            \
  } while (0)

template <bool BF16OUT>
__global__ __launch_bounds__(512, 2) void k_gemm256(const u16* __restrict__ A,
                                                    const u16* __restrict__ Bm,
                                                    void* __restrict__ Cv,
                                                    int M, int N, int K) {
  __shared__ __align__(16) u16 SA[2][256 * 64];
  __shared__ __align__(16) u16 SB[2][256 * 64];
  const int tid = threadIdx.x;
  const int w = tid >> 6, lane = tid & 63;
  const int g = lane >> 4, t = lane & 15;
  const int wr = w >> 2, wc = w & 3;
  const int MBt = M >> 8;
  const int cpx = gridDim.x >> 3;                 // grid %8 == 0 (384 / 256)
  const int swz = (blockIdx.x & 7) * cpx + (blockIdx.x >> 3);
  const int bm = swz % MBt, bn = swz / MBt;       // column-major tile order
  const int m0 = bm << 8, n0 = bn << 8;

  const char* Ab = (const char*)A;
  const char* Bb = (const char*)Bm;
  const size_t rowK = (size_t)K * 2;              // bytes per input row
  const int srcx = ((lane & 7) ^ (lane >> 3)) << 4;  // pre-swizzled src col
  const int l3 = lane >> 3;
  const int tx = (t & 7) << 4;                    // read-side XOR (bytes)

  auto SToff = [&](int h, int j) -> int {
    int ii = w * 2 + j;
    return (ii < 8) ? (h * 64 + ii * 8) : (128 + h * 64 + (ii - 8) * 8);
  };
  auto STAGE_A = [&](int p, int T, int h) {
#pragma unroll
    for (int j = 0; j < 2; ++j) {
      int rb = SToff(h, j);
      GLDS(Ab + (size_t)(m0 + rb + l3) * rowK + (size_t)T * 128 + srcx,
           &SA[p][rb * 64]);
    }
  };
  auto STAGE_B = [&](int p, int T, int h) {
#pragma unroll
    for (int j = 0; j < 2; ++j) {
      int rb = SToff(h, j);
      GLDS(Bb + (size_t)(n0 + rb + l3) * rowK + (size_t)T * 128 + srcx,
           &SB[p][rb * 64]);
    }
  };
  auto LDA = [&](int p, int q, int fr, int kk) -> bf16x8 {
    int ar = wr * 128 + q * 32 + fr * 16 + t;
    const char* ptr = (const char*)&SA[p][0] + ar * 128 + ((kk * 64 + 16 * g) ^ tx);
    return __builtin_bit_cast(bf16x8, *(const u16x8*)ptr);
  };
  auto LDB = [&](int p, int nf, int kk) -> bf16x8 {
    int br = wc * 64 + nf * 16 + t;
    const char* ptr = (const char*)&SB[p][0] + br * 128 + ((kk * 64 + 16 * g) ^ tx);
    return __builtin_bit_cast(bf16x8, *(const u16x8*)ptr);
  };

  f32x4 acc[8][4];
#pragma unroll
  for (int i = 0; i < 8; ++i)
#pragma unroll
    for (int j = 0; j < 4; ++j) acc[i][j] = (f32x4){0.f, 0.f, 0.f, 0.f};
  bf16x8 bfr[4][2];
  bf16x8 afr[2][4];

  // prologue: T0 complete (8 loads) + T1.{A0,B0,B1} (6 loads)
  STAGE_A(0, 0, 0); STAGE_B(0, 0, 0); STAGE_A(0, 0, 1); STAGE_B(0, 0, 1);
  STAGE_A(1, 1, 0); STAGE_B(1, 1, 0); STAGE_B(1, 1, 1);
  VM6;                                            // T0 landed
  __builtin_amdgcn_s_barrier();

  const int NI = (K >> 7) - 1;
  for (int i = 0; i < NI; ++i) {
    const int T1 = 2 * i + 1, T2 = 2 * i + 2, T3 = 2 * i + 3;
    LOADB8(0); LOADA4(0, 0, 0);
    STAGE_A(1, T1, 1); LOADA4(0, 1, 1); MMA16(0, 0); BARX;
    STAGE_B(0, T2, 0); LOADA4(0, 2, 0); MMA16(1, 1); BARX;
    STAGE_B(0, T2, 1); LOADA4(0, 3, 1); MMA16(2, 0); BARX;
    STAGE_A(0, T2, 0); MMA16(3, 1); VM6; BARX;
    LOADB8(1); LOADA4(1, 0, 0);
    STAGE_A(0, T2, 1); LOADA4(1, 1, 1); MMA16(0, 0); BARX;
    STAGE_B(1, T3, 0); LOADA4(1, 2, 0); MMA16(1, 1); BARX;
    STAGE_A(1, T3, 0); LOADA4(1, 3, 1); MMA16(2, 0); BARX;
    STAGE_B(1, T3, 1); MMA16(3, 1); VM6; BARX;
  }
  {                                               // peeled final iteration
    const int TL = (K >> 6) - 1;
    LOADB8(0); LOADA4(0, 0, 0);
    STAGE_A(1, TL, 1); LOADA4(0, 1, 1); MMA16(0, 0); BARX;
    LOADA4(0, 2, 0); MMA16(1, 1); BARX;
    LOADA4(0, 3, 1); MMA16(2, 0); BARX;
    MMA16(3, 1); VM0; BARX;
    LOADB8(1); LOADA4(1, 0, 0);
    LOADA4(1, 1, 1); MMA16(0, 0); BARX;
    LOADA4(1, 2, 0); MMA16(1, 1); BARX;
    LOADA4(1, 3, 1); MMA16(2, 0); BARX;
    MMA16(3, 1);
  }

  // epilogue: C-write (row = 4*(lane>>4)+reg, col = lane&15)
#pragma unroll
  for (int fi = 0; fi < 8; ++fi)
#pragma unroll
    for (int nf = 0; nf < 4; ++nf)
#pragma unroll
      for (int r = 0; r < 4; ++r) {
        int row = m0 + wr * 128 + fi * 16 + 4 * g + r;
        int col = n0 + wc * 64 + nf * 16 + t;
        float v = acc[fi][nf][r];
        if constexpr (BF16OUT) ((u16*)Cv)[(size_t)row * N + col] = f2bf(v);
        else                   ((float*)Cv)[(size_t)row * N + col] = v;
      }
}

// ---------------- flash attention: 8-wave swapped-QK^T 32x32 ----------------
// v2: base-2 softmax (Q pre-scaled by log2e in k_rope; exp2f = 1 HW op) and
// T13 defer-max (THR=4): skip O-rescale when tile max <= m+4 wave-wide.
__global__ __launch_bounds__(512, 2) void k_attn(const u16* __restrict__ Qr,
                                                 const u16* __restrict__ Kr,
                                                 const u16* __restrict__ Vt,
                                                 u16* __restrict__ AO) {
  __shared__ __align__(16) u16 Kl[2][64 * 128];  // [k][d] swizzled
  __shared__ __align__(16) u16 Vl[2][128 * 64];  // [d][k] swizzled
  const int tid = threadIdx.x;
  const int w = tid >> 6, lane = tid & 63;
  const int q = lane & 31, hi = lane >> 5;
  const int bh = blockIdx.y;
  const int b = bh >> 5, h = bh & 31;
  const int kvh = h >> 2;                        // GQA: H/KV = 4
  const int bxr = gridDim.x - 1 - blockIdx.x;    // longest blocks first
  const int q0 = bxr * 256;
  const int qw = q0 + w * 32;
  const int ntiles = 4 * bxr + 4;
  const int qg = qw + q;

  const u16* Qb = Qr + ((size_t)bh * Ssz + qw + q) * Dsz + hi * 8;
  bf16x8 qf[8];
#pragma unroll
  for (int ds = 0; ds < 8; ++ds)
    qf[ds] = __builtin_bit_cast(bf16x8, *(const u16x8*)(Qb + ds * 16));

  f32x16 oacc[4];
#pragma unroll
  for (int dt = 0; dt < 4; ++dt)
#pragma unroll
    for (int r = 0; r < 16; ++r) oacc[dt][r] = 0.f;
  float mr = -1e30f, lr = 0.f;

  const char* Kbase = (const char*)(Kr + (size_t)(b * KVsz + kvh) * Ssz * Dsz);
  const char* Vbase = (const char*)(Vt + (size_t)(b * KVsz + kvh) * Dsz * Ssz);

  auto STAGE = [&](int bu, int kt2) {
    const char* Kb = Kbase + (size_t)kt2 * (64 * 256);
    const char* Vb = Vbase + (size_t)kt2 * 128;   // 64 cols * 2B
#pragma unroll
    for (int j = 0; j < 2; ++j) {
      int flat = j * 512 + tid;
      int row = flat >> 4, colb = ((flat & 15) * 16) ^ ((row & 7) << 4);
      GLDS(Kb + (size_t)row * 256 + colb, (char*)&Kl[bu][0] + flat * 16);
    }
#pragma unroll
    for (int j = 0; j < 2; ++j) {
      int flat = j * 512 + tid;
      int row = flat >> 3, colb = ((flat & 7) * 16) ^ ((row & 7) << 4);
      GLDS(Vb + (size_t)row * (Ssz * 2) + colb, (char*)&Vl[bu][0] + flat * 16);
    }
  };

  int buf = 0;
  STAGE(0, 0);
  __syncthreads();

  for (int kt = 0; kt < ntiles; ++kt) {
    const int k0 = kt * 64;
    if (kt + 1 < ntiles) STAGE(buf ^ 1, kt + 1);   // prefetch overlaps compute

    if (k0 <= qw + 31) {                           // wave participates
      f32x16 pa0, pa1;
#pragma unroll
      for (int r = 0; r < 16; ++r) { pa0[r] = 0.f; pa1[r] = 0.f; }
      __builtin_amdgcn_s_setprio(1);
#pragma unroll
      for (int ds = 0; ds < 8; ++ds) {
        {
          const int row = q;
          const char* kp = (const char*)&Kl[buf][0] + row * 256 +
                           ((ds * 32 + hi * 16) ^ ((row & 7) << 4));
          bf16x8 kf = __builtin_bit_cast(bf16x8, *(const u16x8*)kp);
          pa0 = __builtin_amdgcn_mfma_f32_32x32x16_bf16(kf, qf[ds], pa0, 0, 0, 0);
        }
        {
          const int row = 32 + q;
          const char* kp = (const char*)&Kl[buf][0] + row * 256 +
                           ((ds * 32 + hi * 16) ^ ((row & 7) << 4));
          bf16x8 kf = __builtin_bit_cast(bf16x8, *(const u16x8*)kp);
          pa1 = __builtin_amdgcn_mfma_f32_32x32x16_bf16(kf, qf[ds], pa1, 0, 0, 0);
        }
      }
      __builtin_amdgcn_s_setprio(0);

      if (k0 + 63 > qw) {
#pragma unroll
        for (int reg = 0; reg < 16; ++reg) {
          const int kb = (reg & 3) + 8 * (reg >> 2) + 4 * hi;
          if (k0 + kb > qg)      pa0[reg] = -1e30f;
          if (k0 + 32 + kb > qg) pa1[reg] = -1e30f;
        }
      }
      // online softmax (base 2), lane-local row; T13 defer-max THR=4
      float mx = -1e30f;
#pragma unroll
      for (int reg = 0; reg < 16; ++reg) mx = fmaxf(mx, fmaxf(pa0[reg], pa1[reg]));
      mx = fmaxf(mx, __shfl_xor(mx, 32, 64));
      if (!__all(mx <= mr + 4.0f)) {
        const float mnew = fmaxf(mr, mx);
        const float corr = exp2f(mr - mnew);
        lr *= corr;
#pragma unroll
        for (int dt = 0; dt < 4; ++dt)
#pragma unroll
          for (int reg = 0; reg < 16; ++reg) oacc[dt][reg] *= corr;
        mr = mnew;
      }
      float ps = 0.f;
#pragma unroll
      for (int reg = 0; reg < 16; ++reg) {
        pa0[reg] = exp2f(pa0[reg] - mr);
        pa1[reg] = exp2f(pa1[reg] - mr);
        ps += pa0[reg] + pa1[reg];
      }
      ps += __shfl_xor(ps, 32, 64);
      lr += ps;

      uint32_t W[2][4][2], X[2][4][2];
#pragma unroll
      for (int r2 = 0; r2 < 4; ++r2)
#pragma unroll
        for (int c = 0; c < 2; ++c) {
          W[0][r2][c] = packbf2(pa0[4 * r2 + 2 * c], pa0[4 * r2 + 2 * c + 1]);
          W[1][r2][c] = packbf2(pa1[4 * r2 + 2 * c], pa1[4 * r2 + 2 * c + 1]);
        }
#pragma unroll
      for (int T = 0; T < 2; ++T)
#pragma unroll
        for (int r2 = 0; r2 < 4; ++r2)
#pragma unroll
          for (int c = 0; c < 2; ++c)
            X[T][r2][c] = __shfl_xor(W[T][r2][c], 32, 64);

      __builtin_amdgcn_s_setprio(1);
#pragma unroll
      for (int ks = 0; ks < 4; ++ks) {
        const int T = ks >> 1, r2e = 2 * (ks & 1);
        u32x4 fw;
        fw[0] = hi ? X[T][r2e + 1][0] : W[T][r2e][0];
        fw[1] = hi ? X[T][r2e + 1][1] : W[T][r2e][1];
        fw[2] = hi ? W[T][r2e + 1][0] : X[T][r2e][0];
        fw[3] = hi ? W[T][r2e + 1][1] : X[T][r2e][1];
        bf16x8 pf = __builtin_bit_cast(bf16x8, fw);
#pragma unroll
        for (int dt = 0; dt < 4; ++dt) {
          const int row = dt * 32 + q;
          const char* vp = (const char*)&Vl[buf][0] + row * 128 +
                           ((ks * 32 + hi * 16) ^ ((row & 7) << 4));
          bf16x8 vf = __builtin_bit_cast(bf16x8, *(const u16x8*)vp);
          oacc[dt] = __builtin_amdgcn_mfma_f32_32x32x16_bf16(vf, pf, oacc[dt], 0, 0, 0);
        }
      }
      __builtin_amdgcn_s_setprio(0);
    }
    __syncthreads();                             // drains vmcnt: next buffer ready
    buf ^= 1;
  }

  const float inv = 1.f / lr;
  u16* Ob = AO + ((size_t)(b * Ssz) + qw + q) * HIDsz + h * Dsz + hi * 4;
#pragma unroll
  for (int dt = 0; dt < 4; ++dt)
#pragma unroll
    for (int r2 = 0; r2 < 4; ++r2) {
      u16x4 o4;
#pragma unroll
      for (int j = 0; j < 4; ++j) o4[j] = f2bf(oacc[dt][4 * r2 + j] * inv);
      *(u16x4*)(Ob + dt * 32 + r2 * 8) = o4;
    }
}

// ---------------- host ----------------
extern "C" void kernel_launch(void* const* d_in, const int* in_sizes, int n_in,
                              void* d_out, int out_size, void* d_ws, size_t ws_size,
                              hipStream_t stream) {
  (void)in_sizes; (void)n_in; (void)out_size;
  const float* hs   = (const float*)d_in[0];
  const int*   pos  = (const int*)d_in[1];
  const float* Wqkv = (const float*)d_in[2];
  const float* Wo   = (const float*)d_in[3];

  char* ws = (char*)d_ws;
  const size_t SZ_XBF = (size_t)4096 * 4096 * 2;   // also reused for AO
  const size_t SZ_WQ  = (size_t)6144 * 4096 * 2;
  const size_t SZ_WO  = (size_t)4096 * 4096 * 2;
  const size_t SZ_QKV = (size_t)4096 * 6144 * 2;
  const size_t SZ_QR  = (size_t)Bsz * Hsz * Ssz * Dsz * 2;
  const size_t SZ_KR  = (size_t)Bsz * KVsz * Ssz * Dsz * 2;
  const size_t SZ_VT  = SZ_KR;

  size_t off = 0;
  u16*   Xbf   = (u16*)(ws + off);  off += SZ_XBF;
  u16*   Wq_bf = (u16*)(ws + off);  off += SZ_WQ;
  u16*   Wo_bf = (u16*)(ws + off);  off += SZ_WO;
  u16*   qkv   = (u16*)(ws + off);  off += SZ_QKV;
  u16*   Qr    = (u16*)(ws + off);  off += SZ_QR;
  u16*   Kr    = (u16*)(ws + off);  off += SZ_KR;
  u16*   Vt    = (u16*)(ws + off);  off += SZ_VT;
  u16*   AO    = Xbf;                               // alias (Xbf dead after gemm1)
  if (ws_size < off) return;                        // fail loudly

  // 1. fp32 -> bf16 conversions (single launch)
  k_cvt3<<<(N4_HS + N4_WQ + N4_WO + 255) / 256, 256, 0, stream>>>(
      hs, Wqkv, Wo, Xbf, Wq_bf, Wo_bf);

  // 2. QKV projection: [4096,4096] x [6144,4096]^T -> [4096,6144]
  k_gemm256<true><<<dim3((NQKV / 256) * ((Bsz * Ssz) / 256)), 512, 0, stream>>>(
      Xbf, Wq_bf, qkv, Bsz * Ssz, NQKV, HIDsz);

  // 3. RoPE (inline sincos) + V transpose
  k_rope<<<(Bsz * Ssz * (Hsz + KVsz) * 64) / 256, 256, 0, stream>>>(qkv, pos, Qr, Kr);
  k_vtrans<<<dim3(64, Bsz * KVsz), 256, 0, stream>>>(qkv, Vt);

  // 4. causal GQA attention -> AO [B,S,H*D] bf16
  k_attn<<<dim3(Ssz / 256, Bsz * Hsz), 512, 0, stream>>>(Qr, Kr, Vt, AO);

  // 5. o_proj: [4096,4096] x [4096,4096]^T -> d_out fp32
  k_gemm256<false><<<dim3((HIDsz / 256) * ((Bsz * Ssz) / 256)), 512, 0, stream>>>(
      AO, Wo_bf, (float*)d_out, Bsz * Ssz, HIDsz, HIDsz);
}

// Round 9
// 586.434 us; speedup vs baseline: 1.1583x; 1.1583x over previous
//
#include <hip/hip_runtime.h>
#include <stdint.h>
#include <stddef.h>

#define Bsz   2
#define Ssz   2048
#define HIDsz 4096
#define Hsz   32
#define KVsz  8
#define Dsz   128
#define NQKV  6144                     // (H+2KV)*D
// Q scale = 1/sqrt(128) * log2(e): softmax computed base-2 (exp2 is the HW op)
#define QSCALE 0.12752057463f
#define L2_1E4_64 0.20762050595f       // log2(10000)/64

typedef __bf16 bf16x8 __attribute__((ext_vector_type(8)));
typedef float  f32x4  __attribute__((ext_vector_type(4)));
typedef float  f32x16 __attribute__((ext_vector_type(16)));
typedef unsigned short u16;
typedef u16 u16x4 __attribute__((ext_vector_type(4)));
typedef u16 u16x8 __attribute__((ext_vector_type(8)));
typedef uint32_t u32x4 __attribute__((ext_vector_type(4)));

__device__ __forceinline__ u16 f2bf(float f) {
  uint32_t u = __builtin_bit_cast(uint32_t, f);
  u = (u + 0x7FFFu + ((u >> 16) & 1u)) >> 16;   // RNE
  return (u16)u;
}
__device__ __forceinline__ u16 f2bf_fast(float f) {  // round-half-up, 2 VALU
  uint32_t u = __builtin_bit_cast(uint32_t, f);
  return (u16)((u + 0x8000u) >> 16);
}
__device__ __forceinline__ float bf2f(u16 h) {
  return __builtin_bit_cast(float, (uint32_t)h << 16);
}
__device__ __forceinline__ uint32_t packbf2(float lo, float hi_) {
  return (uint32_t)f2bf_fast(lo) | ((uint32_t)f2bf_fast(hi_) << 16);
}

// global -> LDS async copy, 16B per lane; LDS dest = wave-uniform base + lane*16
#define GLDS(gp, lp) __builtin_amdgcn_global_load_lds( \
    (__attribute__((address_space(1))) void*)(void*)(gp), \
    (__attribute__((address_space(3))) void*)(lp), 16, 0, 0)

// ---------------- fused fp32->bf16 conversion (one launch, 3 tensors) -------
#define N4_HS  ((Bsz * Ssz * HIDsz) / 4)
#define N4_WQ  ((NQKV * HIDsz) / 4)
#define N4_WO  ((HIDsz * HIDsz) / 4)
__global__ __launch_bounds__(256) void k_cvt3(const float* __restrict__ hs,
                                              const float* __restrict__ wqkv,
                                              const float* __restrict__ wo,
                                              u16* __restrict__ xbf,
                                              u16* __restrict__ wqbf,
                                              u16* __restrict__ wobf) {
  int i = blockIdx.x * 256 + threadIdx.x;
  const float* src; u16* dst; int off;
  if (i < N4_HS)                   { src = hs;   dst = xbf;  off = i; }
  else if (i < N4_HS + N4_WQ)      { src = wqkv; dst = wqbf; off = i - N4_HS; }
  else if (i < N4_HS + N4_WQ + N4_WO) { src = wo; dst = wobf; off = i - N4_HS - N4_WQ; }
  else return;
  float4 v = ((const float4*)src)[off];
  u16x4 o;
  o.x = f2bf(v.x); o.y = f2bf(v.y); o.z = f2bf(v.z); o.w = f2bf(v.w);
  ((u16x4*)dst)[off] = o;
}

// ============ 256x256 8-phase GEMM: C[M][N] = A[M][K] * B[N][K]^T ============
// MODE 0: plain fp32 C-write (o_proj). LDS = SA[2]+SB[2] = 131072 B.
// MODE 1: fused QKV epilogue — acc staged to a 256xTLS LDS tile (132096 B,
//   gfx950 allows 160 KiB/WG), then per-region transform: Q/K tiles apply RoPE
//   (inline sincos; Q pre-scaled by QSCALE incl. log2e) writing Qr/Kr[bh][s][d];
//   V tiles write transposed Vt[bk][d][s]. Region is block-uniform (n0).
// r8 BUG FIXED: MODE 0 LDS was under-allocated (65536) -> SB lived out of
// bounds -> DS writes dropped, reads 0 -> o_proj output was all zeros.
// Sync structure = r5-r7 (single barrier/phase, A-frag prefetch, vmcnt(6));
// column-major tile order; launch_bounds (512,1).

#define BARX do { asm volatile("" ::: "memory"); __builtin_amdgcn_s_barrier(); \
                  asm volatile("" ::: "memory"); } while (0)
#define VM6  asm volatile("s_waitcnt vmcnt(6)" ::: "memory")
#define VM0  asm volatile("s_waitcnt vmcnt(0)" ::: "memory")

#define LOADA4(P_, Q_, F_) do {                                               \
    afr[F_][0] = LDA(P_, Q_, 0, 0); afr[F_][1] = LDA(P_, Q_, 0, 1);           \
    afr[F_][2] = LDA(P_, Q_, 1, 0); afr[F_][3] = LDA(P_, Q_, 1, 1);           \
  } while (0)

#define LOADB8(P_) do {                                                       \
    _Pragma("unroll") for (int nf = 0; nf < 4; ++nf) {                        \
      bfr[nf][0] = LDB(P_, nf, 0); bfr[nf][1] = LDB(P_, nf, 1); }             \
  } while (0)

#define MMA16(Q_, F_) do {                                                    \
    __builtin_amdgcn_s_setprio(1);                                            \
    _Pragma("unroll") for (int nf = 0; nf < 4; ++nf) {                        \
      acc[(Q_)*2][nf]   = __builtin_amdgcn_mfma_f32_16x16x32_bf16(afr[F_][0], bfr[nf][0], acc[(Q_)*2][nf],   0,0,0); \
      acc[(Q_)*2+1][nf] = __builtin_amdgcn_mfma_f32_16x16x32_bf16(afr[F_][2], bfr[nf][0], acc[(Q_)*2+1][nf], 0,0,0); \
    }                                                                         \
    _Pragma("unroll") for (int nf = 0; nf < 4; ++nf) {                        \
      acc[(Q_)*2][nf]   = __builtin_amdgcn_mfma_f32_16x16x32_bf16(afr[F_][1], bfr[nf][1], acc[(Q_)*2][nf],   0,0,0); \
      acc[(Q_)*2+1][nf] = __builtin_amdgcn_mfma_f32_16x16x32_bf16(afr[F_][3], bfr[nf][1], acc[(Q_)*2+1][nf], 0,0,0); \
    }                                                                         \
    __builtin_amdgcn_s_setprio(0);                                            \
  } while (0)

#define TLS 258                         // epilogue LDS tile stride (u16)

template <int MODE>
__global__ __launch_bounds__(512, 1) void k_gemm256(const u16* __restrict__ A,
                                                    const u16* __restrict__ Bm,
                                                    float* __restrict__ Cv,
                                                    const int* __restrict__ pos,
                                                    u16* __restrict__ Qr,
                                                    u16* __restrict__ Kr,
                                                    u16* __restrict__ Vt,
                                                    int M, int N, int K) {
  constexpr int LDS_BYTES = MODE ? (256 * TLS * 2) : (4 * 256 * 64 * 2);
  __shared__ __align__(16) char LDSBUF[LDS_BYTES];
  u16* SA0 = (u16*)LDSBUF;                        // SA[2][256*64]
  u16* SB0 = (u16*)(LDSBUF + 65536);              // SB[2][256*64]
  const int tid = threadIdx.x;
  const int w = tid >> 6, lane = tid & 63;
  const int g = lane >> 4, t = lane & 15;
  const int wr = w >> 2, wc = w & 3;
  const int MBt = M >> 8;
  const int cpx = gridDim.x >> 3;                 // grid %8 == 0 (384 / 256)
  const int swz = (blockIdx.x & 7) * cpx + (blockIdx.x >> 3);
  const int bm = swz % MBt, bn = swz / MBt;       // column-major tile order
  const int m0 = bm << 8, n0 = bn << 8;

  const char* Ab = (const char*)A;
  const char* Bb = (const char*)Bm;
  const size_t rowK = (size_t)K * 2;              // bytes per input row
  const int srcx = ((lane & 7) ^ (lane >> 3)) << 4;  // pre-swizzled src col
  const int l3 = lane >> 3;
  const int tx = (t & 7) << 4;                    // read-side XOR (bytes)

  auto SToff = [&](int h, int j) -> int {
    int ii = w * 2 + j;
    return (ii < 8) ? (h * 64 + ii * 8) : (128 + h * 64 + (ii - 8) * 8);
  };
  auto STAGE_A = [&](int p, int T, int h) {
#pragma unroll
    for (int j = 0; j < 2; ++j) {
      int rb = SToff(h, j);
      GLDS(Ab + (size_t)(m0 + rb + l3) * rowK + (size_t)T * 128 + srcx,
           &SA0[p * 16384 + rb * 64]);
    }
  };
  auto STAGE_B = [&](int p, int T, int h) {
#pragma unroll
    for (int j = 0; j < 2; ++j) {
      int rb = SToff(h, j);
      GLDS(Bb + (size_t)(n0 + rb + l3) * rowK + (size_t)T * 128 + srcx,
           &SB0[p * 16384 + rb * 64]);
    }
  };
  auto LDA = [&](int p, int q, int fr, int kk) -> bf16x8 {
    int ar = wr * 128 + q * 32 + fr * 16 + t;
    const char* ptr = (const char*)&SA0[p * 16384] + ar * 128 + ((kk * 64 + 16 * g) ^ tx);
    return __builtin_bit_cast(bf16x8, *(const u16x8*)ptr);
  };
  auto LDB = [&](int p, int nf, int kk) -> bf16x8 {
    int br = wc * 64 + nf * 16 + t;
    const char* ptr = (const char*)&SB0[p * 16384] + br * 128 + ((kk * 64 + 16 * g) ^ tx);
    return __builtin_bit_cast(bf16x8, *(const u16x8*)ptr);
  };

  f32x4 acc[8][4];
#pragma unroll
  for (int i = 0; i < 8; ++i)
#pragma unroll
    for (int j = 0; j < 4; ++j) acc[i][j] = (f32x4){0.f, 0.f, 0.f, 0.f};
  bf16x8 bfr[4][2];
  bf16x8 afr[2][4];

  // prologue: T0 complete (8 loads) + T1.{A0,B0,B1} (6 loads)
  STAGE_A(0, 0, 0); STAGE_B(0, 0, 0); STAGE_A(0, 0, 1); STAGE_B(0, 0, 1);
  STAGE_A(1, 1, 0); STAGE_B(1, 1, 0); STAGE_B(1, 1, 1);
  VM6;                                            // T0 landed
  __builtin_amdgcn_s_barrier();

  const int NI = (K >> 7) - 1;
  for (int i = 0; i < NI; ++i) {
    const int T1 = 2 * i + 1, T2 = 2 * i + 2, T3 = 2 * i + 3;
    LOADB8(0); LOADA4(0, 0, 0);
    STAGE_A(1, T1, 1); LOADA4(0, 1, 1); MMA16(0, 0); BARX;
    STAGE_B(0, T2, 0); LOADA4(0, 2, 0); MMA16(1, 1); BARX;
    STAGE_B(0, T2, 1); LOADA4(0, 3, 1); MMA16(2, 0); BARX;
    STAGE_A(0, T2, 0); MMA16(3, 1); VM6; BARX;
    LOADB8(1); LOADA4(1, 0, 0);
    STAGE_A(0, T2, 1); LOADA4(1, 1, 1); MMA16(0, 0); BARX;
    STAGE_B(1, T3, 0); LOADA4(1, 2, 0); MMA16(1, 1); BARX;
    STAGE_A(1, T3, 0); LOADA4(1, 3, 1); MMA16(2, 0); BARX;
    STAGE_B(1, T3, 1); MMA16(3, 1); VM6; BARX;
  }
  {                                               // peeled final iteration
    const int TL_ = (K >> 6) - 1;
    LOADB8(0); LOADA4(0, 0, 0);
    STAGE_A(1, TL_, 1); LOADA4(0, 1, 1); MMA16(0, 0); BARX;
    LOADA4(0, 2, 0); MMA16(1, 1); BARX;
    LOADA4(0, 3, 1); MMA16(2, 0); BARX;
    MMA16(3, 1); VM0; BARX;
    LOADB8(1); LOADA4(1, 0, 0);
    LOADA4(1, 1, 1); MMA16(0, 0); BARX;
    LOADA4(1, 2, 0); MMA16(1, 1); BARX;
    LOADA4(1, 3, 1); MMA16(2, 0); BARX;
    MMA16(3, 1);
  }

  if constexpr (MODE == 0) {
    // plain epilogue: fp32 C-write (row = 4*(lane>>4)+reg, col = lane&15)
#pragma unroll
    for (int fi = 0; fi < 8; ++fi)
#pragma unroll
      for (int nf = 0; nf < 4; ++nf)
#pragma unroll
        for (int r = 0; r < 4; ++r) {
          int row = m0 + wr * 128 + fi * 16 + 4 * g + r;
          int col = n0 + wc * 64 + nf * 16 + t;
          Cv[(size_t)row * N + col] = acc[fi][nf][r];
        }
  } else {
    // fused QKV epilogue
    u16* TL = (u16*)LDSBUF;                       // [256][TLS]
    __syncthreads();                              // all LDS reads of K-loop done
#pragma unroll
    for (int fi = 0; fi < 8; ++fi)
#pragma unroll
      for (int nf = 0; nf < 4; ++nf)
#pragma unroll
        for (int r = 0; r < 4; ++r)
          TL[(wr * 128 + fi * 16 + 4 * g + r) * TLS + wc * 64 + nf * 16 + t] =
              f2bf(acc[fi][nf][r]);
    __syncthreads();

    if (n0 < (Hsz + KVsz) * Dsz) {
      // Q or K region: RoPE. wave processes one (row, head-half) per iter.
      const bool isQ = (n0 < Hsz * Dsz);
      const int j = lane;                         // 0..63 = pair index
      const float ifr = exp2f(-(float)j * L2_1E4_64);
#pragma unroll 1
      for (int it = 0; it < 64; ++it) {
        int combo = w * 64 + it;                  // 0..511
        int row = combo & 255;
        int hh = combo >> 8;                      // 0/1: head within tile
        int tok = m0 + row;
        int b = tok >> 11, s = tok & (Ssz - 1);
        float x1 = bf2f(TL[row * TLS + hh * 128 + j]);
        float x2 = bf2f(TL[row * TLS + hh * 128 + 64 + j]);
        float p = (float)pos[tok];
        float ang = p * ifr;
        float sn, cs;
        __sincosf(ang, &sn, &cs);
        float o1 = x1 * cs - x2 * sn;
        float o2 = x2 * cs + x1 * sn;
        u16* o;
        if (isQ) {
          int h = (n0 >> 7) + hh;
          o = Qr + ((size_t)(b * Hsz + h) * Ssz + s) * Dsz;
          o1 *= QSCALE; o2 *= QSCALE;
        } else {
          int kvh = ((n0 - Hsz * Dsz) >> 7) + hh;
          o = Kr + ((size_t)(b * KVsz + kvh) * Ssz + s) * Dsz;
        }
        o[j] = f2bf(o1); o[j + 64] = f2bf(o2);
      }
    } else {
      // V region: transposed write Vt[bk][d][s]; wave per d-col, lane per 4-tok
      const int dbase = n0 - (Hsz + KVsz) * Dsz;  // 0..1023
#pragma unroll 1
      for (int it = 0; it < 32; ++it) {
        int col = w * 32 + it;                    // 0..255
        int dg = dbase + col;
        int kvh = dg >> 7, d = dg & 127;
        int tok0 = m0 + 4 * lane;
        int b = tok0 >> 11, s0 = tok0 & (Ssz - 1);
        u16x4 v4;
#pragma unroll
        for (int i2 = 0; i2 < 4; ++i2)
          v4[i2] = TL[(4 * lane + i2) * TLS + col];
        *(u16x4*)(Vt + ((size_t)(b * KVsz + kvh) * Dsz + d) * Ssz + s0) = v4;
      }
    }
  }
}

// ---------------- flash attention: 8-wave swapped-QK^T 32x32 ----------------
// base-2 softmax (Q pre-scaled by log2e) and T13 defer-max (THR=4).
__global__ __launch_bounds__(512, 2) void k_attn(const u16* __restrict__ Qr,
                                                 const u16* __restrict__ Kr,
                                                 const u16* __restrict__ Vt,
                                                 u16* __restrict__ AO) {
  __shared__ __align__(16) u16 Kl[2][64 * 128];  // [k][d] swizzled
  __shared__ __align__(16) u16 Vl[2][128 * 64];  // [d][k] swizzled
  const int tid = threadIdx.x;
  const int w = tid >> 6, lane = tid & 63;
  const int q = lane & 31, hi = lane >> 5;
  const int bh = blockIdx.y;
  const int b = bh >> 5, h = bh & 31;
  const int kvh = h >> 2;                        // GQA: H/KV = 4
  const int bxr = gridDim.x - 1 - blockIdx.x;    // longest blocks first
  const int q0 = bxr * 256;
  const int qw = q0 + w * 32;
  const int ntiles = 4 * bxr + 4;
  const int qg = qw + q;

  const u16* Qb = Qr + ((size_t)bh * Ssz + qw + q) * Dsz + hi * 8;
  bf16x8 qf[8];
#pragma unroll
  for (int ds = 0; ds < 8; ++ds)
    qf[ds] = __builtin_bit_cast(bf16x8, *(const u16x8*)(Qb + ds * 16));

  f32x16 oacc[4];
#pragma unroll
  for (int dt = 0; dt < 4; ++dt)
#pragma unroll
    for (int r = 0; r < 16; ++r) oacc[dt][r] = 0.f;
  float mr = -1e30f, lr = 0.f;

  const char* Kbase = (const char*)(Kr + (size_t)(b * KVsz + kvh) * Ssz * Dsz);
  const char* Vbase = (const char*)(Vt + (size_t)(b * KVsz + kvh) * Dsz * Ssz);

  auto STAGE = [&](int bu, int kt2) {
    const char* Kb = Kbase + (size_t)kt2 * (64 * 256);
    const char* Vb = Vbase + (size_t)kt2 * 128;   // 64 cols * 2B
#pragma unroll
    for (int j = 0; j < 2; ++j) {
      int flat = j * 512 + tid;
      int row = flat >> 4, colb = ((flat & 15) * 16) ^ ((row & 7) << 4);
      GLDS(Kb + (size_t)row * 256 + colb, (char*)&Kl[bu][0] + flat * 16);
    }
#pragma unroll
    for (int j = 0; j < 2; ++j) {
      int flat = j * 512 + tid;
      int row = flat >> 3, colb = ((flat & 7) * 16) ^ ((row & 7) << 4);
      GLDS(Vb + (size_t)row * (Ssz * 2) + colb, (char*)&Vl[bu][0] + flat * 16);
    }
  };

  int buf = 0;
  STAGE(0, 0);
  __syncthreads();

  for (int kt = 0; kt < ntiles; ++kt) {
    const int k0 = kt * 64;
    if (kt + 1 < ntiles) STAGE(buf ^ 1, kt + 1);   // prefetch overlaps compute

    if (k0 <= qw + 31) {                           // wave participates
      f32x16 pa0, pa1;
#pragma unroll
      for (int r = 0; r < 16; ++r) { pa0[r] = 0.f; pa1[r] = 0.f; }
      __builtin_amdgcn_s_setprio(1);
#pragma unroll
      for (int ds = 0; ds < 8; ++ds) {
        {
          const int row = q;
          const char* kp = (const char*)&Kl[buf][0] + row * 256 +
                           ((ds * 32 + hi * 16) ^ ((row & 7) << 4));
          bf16x8 kf = __builtin_bit_cast(bf16x8, *(const u16x8*)kp);
          pa0 = __builtin_amdgcn_mfma_f32_32x32x16_bf16(kf, qf[ds], pa0, 0, 0, 0);
        }
        {
          const int row = 32 + q;
          const char* kp = (const char*)&Kl[buf][0] + row * 256 +
                           ((ds * 32 + hi * 16) ^ ((row & 7) << 4));
          bf16x8 kf = __builtin_bit_cast(bf16x8, *(const u16x8*)kp);
          pa1 = __builtin_amdgcn_mfma_f32_32x32x16_bf16(kf, qf[ds], pa1, 0, 0, 0);
        }
      }
      __builtin_amdgcn_s_setprio(0);

      if (k0 + 63 > qw) {
#pragma unroll
        for (int reg = 0; reg < 16; ++reg) {
          const int kb = (reg & 3) + 8 * (reg >> 2) + 4 * hi;
          if (k0 + kb > qg)      pa0[reg] = -1e30f;
          if (k0 + 32 + kb > qg) pa1[reg] = -1e30f;
        }
      }
      // online softmax (base 2), lane-local row; T13 defer-max THR=4
      float mx = -1e30f;
#pragma unroll
      for (int reg = 0; reg < 16; ++reg) mx = fmaxf(mx, fmaxf(pa0[reg], pa1[reg]));
      mx = fmaxf(mx, __shfl_xor(mx, 32, 64));
      if (!__all(mx <= mr + 4.0f)) {
        const float mnew = fmaxf(mr, mx);
        const float corr = exp2f(mr - mnew);
        lr *= corr;
#pragma unroll
        for (int dt = 0; dt < 4; ++dt)
#pragma unroll
          for (int reg = 0; reg < 16; ++reg) oacc[dt][reg] *= corr;
        mr = mnew;
      }
      float ps = 0.f;
#pragma unroll
      for (int reg = 0; reg < 16; ++reg) {
        pa0[reg] = exp2f(pa0[reg] - mr);
        pa1[reg] = exp2f(pa1[reg] - mr);
        ps += pa0[reg] + pa1[reg];
      }
      ps += __shfl_xor(ps, 32, 64);
      lr += ps;

      uint32_t W[2][4][2], X[2][4][2];
#pragma unroll
      for (int r2 = 0; r2 < 4; ++r2)
#pragma unroll
        for (int c = 0; c < 2; ++c) {
          W[0][r2][c] = packbf2(pa0[4 * r2 + 2 * c], pa0[4 * r2 + 2 * c + 1]);
          W[1][r2][c] = packbf2(pa1[4 * r2 + 2 * c], pa1[4 * r2 + 2 * c + 1]);
        }
#pragma unroll
      for (int T = 0; T < 2; ++T)
#pragma unroll
        for (int r2 = 0; r2 < 4; ++r2)
#pragma unroll
          for (int c = 0; c < 2; ++c)
            X[T][r2][c] = __shfl_xor(W[T][r2][c], 32, 64);

      __builtin_amdgcn_s_setprio(1);
#pragma unroll
      for (int ks = 0; ks < 4; ++ks) {
        const int T = ks >> 1, r2e = 2 * (ks & 1);
        u32x4 fw;
        fw[0] = hi ? X[T][r2e + 1][0] : W[T][r2e][0];
        fw[1] = hi ? X[T][r2e + 1][1] : W[T][r2e][1];
        fw[2] = hi ? W[T][r2e + 1][0] : X[T][r2e][0];
        fw[3] = hi ? W[T][r2e + 1][1] : X[T][r2e][1];
        bf16x8 pf = __builtin_bit_cast(bf16x8, fw);
#pragma unroll
        for (int dt = 0; dt < 4; ++dt) {
          const int row = dt * 32 + q;
          const char* vp = (const char*)&Vl[buf][0] + row * 128 +
                           ((ks * 32 + hi * 16) ^ ((row & 7) << 4));
          bf16x8 vf = __builtin_bit_cast(bf16x8, *(const u16x8*)vp);
          oacc[dt] = __builtin_amdgcn_mfma_f32_32x32x16_bf16(vf, pf, oacc[dt], 0, 0, 0);
        }
      }
      __builtin_amdgcn_s_setprio(0);
    }
    __syncthreads();                             // drains vmcnt: next buffer ready
    buf ^= 1;
  }

  const float inv = 1.f / lr;
  u16* Ob = AO + ((size_t)(b * Ssz) + qw + q) * HIDsz + h * Dsz + hi * 4;
#pragma unroll
  for (int dt = 0; dt < 4; ++dt)
#pragma unroll
    for (int r2 = 0; r2 < 4; ++r2) {
      u16x4 o4;
#pragma unroll
      for (int j = 0; j < 4; ++j) o4[j] = f2bf(oacc[dt][4 * r2 + j] * inv);
      *(u16x4*)(Ob + dt * 32 + r2 * 8) = o4;
    }
}

// ---------------- host ----------------
extern "C" void kernel_launch(void* const* d_in, const int* in_sizes, int n_in,
                              void* d_out, int out_size, void* d_ws, size_t ws_size,
                              hipStream_t stream) {
  (void)in_sizes; (void)n_in; (void)out_size;
  const float* hs   = (const float*)d_in[0];
  const int*   pos  = (const int*)d_in[1];
  const float* Wqkv = (const float*)d_in[2];
  const float* Wo   = (const float*)d_in[3];

  char* ws = (char*)d_ws;
  const size_t SZ_XBF = (size_t)4096 * 4096 * 2;   // also reused for AO
  const size_t SZ_WQ  = (size_t)6144 * 4096 * 2;
  const size_t SZ_WO  = (size_t)4096 * 4096 * 2;
  const size_t SZ_QR  = (size_t)Bsz * Hsz * Ssz * Dsz * 2;
  const size_t SZ_KR  = (size_t)Bsz * KVsz * Ssz * Dsz * 2;
  const size_t SZ_VT  = SZ_KR;

  size_t off = 0;
  u16*   Xbf   = (u16*)(ws + off);  off += SZ_XBF;
  u16*   Wq_bf = (u16*)(ws + off);  off += SZ_WQ;
  u16*   Wo_bf = (u16*)(ws + off);  off += SZ_WO;
  u16*   Qr    = (u16*)(ws + off);  off += SZ_QR;
  u16*   Kr    = (u16*)(ws + off);  off += SZ_KR;
  u16*   Vt    = (u16*)(ws + off);  off += SZ_VT;
  u16*   AO    = Xbf;                               // alias (Xbf dead after gemm1)
  if (ws_size < off) return;                        // fail loudly

  // 1. fp32 -> bf16 conversions (single launch)
  k_cvt3<<<(N4_HS + N4_WQ + N4_WO + 255) / 256, 256, 0, stream>>>(
      hs, Wqkv, Wo, Xbf, Wq_bf, Wo_bf);

  // 2. QKV projection fused with RoPE + V-transpose -> Qr, Kr, Vt
  k_gemm256<1><<<dim3((NQKV / 256) * ((Bsz * Ssz) / 256)), 512, 0, stream>>>(
      Xbf, Wq_bf, nullptr, pos, Qr, Kr, Vt, Bsz * Ssz, NQKV, HIDsz);

  // 3. causal GQA attention -> AO [B,S,H*D] bf16
  k_attn<<<dim3(Ssz / 256, Bsz * Hsz), 512, 0, stream>>>(Qr, Kr, Vt, AO);

  // 4. o_proj: [4096,4096] x [4096,4096]^T -> d_out fp32
  k_gemm256<0><<<dim3((HIDsz / 256) * ((Bsz * Ssz) / 256)), 512, 0, stream>>>(
      AO, Wo_bf, (float*)d_out, nullptr, nullptr, nullptr, nullptr,
      Bsz * Ssz, HIDsz, HIDsz);
}

// Round 10
// 541.611 us; speedup vs baseline: 1.2542x; 1.0828x over previous
//
#include <hip/hip_runtime.h>
#include <stdint.h>
#include <stddef.h>

#define Bsz   2
#define Ssz   2048
#define HIDsz 4096
#define Hsz   32
#define KVsz  8
#define Dsz   128
#define NQKV  6144                     // (H+2KV)*D
// Q scale = 1/sqrt(128) * log2(e): softmax computed base-2 (exp2 is the HW op)
#define QSCALE 0.12752057463f
#define L2_1E4_64 0.20762050595f       // log2(10000)/64

typedef __bf16 bf16x8 __attribute__((ext_vector_type(8)));
typedef __bf16 bf16x2 __attribute__((ext_vector_type(2)));
typedef float  f32x4  __attribute__((ext_vector_type(4)));
typedef float  f32x16 __attribute__((ext_vector_type(16)));
typedef unsigned short u16;
typedef u16 u16x4 __attribute__((ext_vector_type(4)));
typedef u16 u16x8 __attribute__((ext_vector_type(8)));
typedef uint32_t u32x4 __attribute__((ext_vector_type(4)));

__device__ __forceinline__ u16 f2bf(float f) {
  uint32_t u = __builtin_bit_cast(uint32_t, f);
  u = (u + 0x7FFFu + ((u >> 16) & 1u)) >> 16;   // RNE
  return (u16)u;
}
__device__ __forceinline__ float bf2f(u16 h) {
  return __builtin_bit_cast(float, (uint32_t)h << 16);
}
// pair pack via compiler (emits v_cvt_pk_bf16_f32 — m240: faster than bit math)
__device__ __forceinline__ uint32_t packc(float lo, float hi_) {
  bf16x2 t;
  t[0] = (__bf16)lo; t[1] = (__bf16)hi_;
  return __builtin_bit_cast(uint32_t, t);
}

// global -> LDS async copy, 16B per lane; LDS dest = wave-uniform base + lane*16
#define GLDS(gp, lp) __builtin_amdgcn_global_load_lds( \
    (__attribute__((address_space(1))) void*)(void*)(gp), \
    (__attribute__((address_space(3))) void*)(lp), 16, 0, 0)

// ---------------- fused fp32->bf16 conversion (one launch, 3 tensors) -------
#define N4_HS  ((Bsz * Ssz * HIDsz) / 4)
#define N4_WQ  ((NQKV * HIDsz) / 4)
#define N4_WO  ((HIDsz * HIDsz) / 4)
__global__ __launch_bounds__(256) void k_cvt3(const float* __restrict__ hs,
                                              const float* __restrict__ wqkv,
                                              const float* __restrict__ wo,
                                              u16* __restrict__ xbf,
                                              u16* __restrict__ wqbf,
                                              u16* __restrict__ wobf) {
  int i = blockIdx.x * 256 + threadIdx.x;
  const float* src; u16* dst; int off;
  if (i < N4_HS)                   { src = hs;   dst = xbf;  off = i; }
  else if (i < N4_HS + N4_WQ)      { src = wqkv; dst = wqbf; off = i - N4_HS; }
  else if (i < N4_HS + N4_WQ + N4_WO) { src = wo; dst = wobf; off = i - N4_HS - N4_WQ; }
  else return;
  float4 v = ((const float4*)src)[off];
  u16x4 o;
  o.x = f2bf(v.x); o.y = f2bf(v.y); o.z = f2bf(v.z); o.w = f2bf(v.w);
  ((u16x4*)dst)[off] = o;
}

// ============ 256x256 8-phase GEMM: C[M][N] = A[M][K] * B[N][K]^T ============
// MODE 0: plain fp32 C-write (o_proj). LDS = SA[2]+SB[2] = 131072 B.
// MODE 1: fused QKV epilogue (RoPE for Q/K regions, transpose for V region).

#define BARX do { asm volatile("" ::: "memory"); __builtin_amdgcn_s_barrier(); \
                  asm volatile("" ::: "memory"); } while (0)
#define VM6  asm volatile("s_waitcnt vmcnt(6)" ::: "memory")
#define VM0  asm volatile("s_waitcnt vmcnt(0)" ::: "memory")

#define LOADA4(P_, Q_, F_) do {                                               \
    afr[F_][0] = LDA(P_, Q_, 0, 0); afr[F_][1] = LDA(P_, Q_, 0, 1);           \
    afr[F_][2] = LDA(P_, Q_, 1, 0); afr[F_][3] = LDA(P_, Q_, 1, 1);           \
  } while (0)

#define LOADB8(P_) do {                                                       \
    _Pragma("unroll") for (int nf = 0; nf < 4; ++nf) {                        \
      bfr[nf][0] = LDB(P_, nf, 0); bfr[nf][1] = LDB(P_, nf, 1); }             \
  } while (0)

#define MMA16(Q_, F_) do {                                                    \
    __builtin_amdgcn_s_setprio(1);                                            \
    _Pragma("unroll") for (int nf = 0; nf < 4; ++nf) {                        \
      acc[(Q_)*2][nf]   = __builtin_amdgcn_mfma_f32_16x16x32_bf16(afr[F_][0], bfr[nf][0], acc[(Q_)*2][nf],   0,0,0); \
      acc[(Q_)*2+1][nf] = __builtin_amdgcn_mfma_f32_16x16x32_bf16(afr[F_][2], bfr[nf][0], acc[(Q_)*2+1][nf], 0,0,0); \
    }                                                                         \
    _Pragma("unroll") for (int nf = 0; nf < 4; ++nf) {                        \
      acc[(Q_)*2][nf]   = __builtin_amdgcn_mfma_f32_16x16x32_bf16(afr[F_][1], bfr[nf][1], acc[(Q_)*2][nf],   0,0,0); \
      acc[(Q_)*2+1][nf] = __builtin_amdgcn_mfma_f32_16x16x32_bf16(afr[F_][3], bfr[nf][1], acc[(Q_)*2+1][nf], 0,0,0); \
    }                                                                         \
    __builtin_amdgcn_s_setprio(0);                                            \
  } while (0)

#define TLS 258                         // epilogue LDS tile stride (u16)

template <int MODE>
__global__ __launch_bounds__(512, 1) void k_gemm256(const u16* __restrict__ A,
                                                    const u16* __restrict__ Bm,
                                                    float* __restrict__ Cv,
                                                    const int* __restrict__ pos,
                                                    u16* __restrict__ Qr,
                                                    u16* __restrict__ Kr,
                                                    u16* __restrict__ Vt,
                                                    int M, int N, int K) {
  constexpr int LDS_BYTES = MODE ? (256 * TLS * 2) : (4 * 256 * 64 * 2);
  __shared__ __align__(16) char LDSBUF[LDS_BYTES];
  u16* SA0 = (u16*)LDSBUF;                        // SA[2][256*64]
  u16* SB0 = (u16*)(LDSBUF + 65536);              // SB[2][256*64]
  const int tid = threadIdx.x;
  const int w = tid >> 6, lane = tid & 63;
  const int g = lane >> 4, t = lane & 15;
  const int wr = w >> 2, wc = w & 3;
  const int MBt = M >> 8;
  const int cpx = gridDim.x >> 3;                 // grid %8 == 0 (384 / 256)
  const int swz = (blockIdx.x & 7) * cpx + (blockIdx.x >> 3);
  const int bm = swz % MBt, bn = swz / MBt;       // column-major tile order
  const int m0 = bm << 8, n0 = bn << 8;

  const char* Ab = (const char*)A;
  const char* Bb = (const char*)Bm;
  const size_t rowK = (size_t)K * 2;              // bytes per input row
  const int srcx = ((lane & 7) ^ (lane >> 3)) << 4;  // pre-swizzled src col
  const int l3 = lane >> 3;
  const int tx = (t & 7) << 4;                    // read-side XOR (bytes)

  auto SToff = [&](int h, int j) -> int {
    int ii = w * 2 + j;
    return (ii < 8) ? (h * 64 + ii * 8) : (128 + h * 64 + (ii - 8) * 8);
  };
  auto STAGE_A = [&](int p, int T, int h) {
#pragma unroll
    for (int j = 0; j < 2; ++j) {
      int rb = SToff(h, j);
      GLDS(Ab + (size_t)(m0 + rb + l3) * rowK + (size_t)T * 128 + srcx,
           &SA0[p * 16384 + rb * 64]);
    }
  };
  auto STAGE_B = [&](int p, int T, int h) {
#pragma unroll
    for (int j = 0; j < 2; ++j) {
      int rb = SToff(h, j);
      GLDS(Bb + (size_t)(n0 + rb + l3) * rowK + (size_t)T * 128 + srcx,
           &SB0[p * 16384 + rb * 64]);
    }
  };
  auto LDA = [&](int p, int q, int fr, int kk) -> bf16x8 {
    int ar = wr * 128 + q * 32 + fr * 16 + t;
    const char* ptr = (const char*)&SA0[p * 16384] + ar * 128 + ((kk * 64 + 16 * g) ^ tx);
    return __builtin_bit_cast(bf16x8, *(const u16x8*)ptr);
  };
  auto LDB = [&](int p, int nf, int kk) -> bf16x8 {
    int br = wc * 64 + nf * 16 + t;
    const char* ptr = (const char*)&SB0[p * 16384] + br * 128 + ((kk * 64 + 16 * g) ^ tx);
    return __builtin_bit_cast(bf16x8, *(const u16x8*)ptr);
  };

  f32x4 acc[8][4];
#pragma unroll
  for (int i = 0; i < 8; ++i)
#pragma unroll
    for (int j = 0; j < 4; ++j) acc[i][j] = (f32x4){0.f, 0.f, 0.f, 0.f};
  bf16x8 bfr[4][2];
  bf16x8 afr[2][4];

  // prologue: T0 complete (8 loads) + T1.{A0,B0,B1} (6 loads)
  STAGE_A(0, 0, 0); STAGE_B(0, 0, 0); STAGE_A(0, 0, 1); STAGE_B(0, 0, 1);
  STAGE_A(1, 1, 0); STAGE_B(1, 1, 0); STAGE_B(1, 1, 1);
  VM6;                                            // T0 landed
  __builtin_amdgcn_s_barrier();

  const int NI = (K >> 7) - 1;
  for (int i = 0; i < NI; ++i) {
    const int T1 = 2 * i + 1, T2 = 2 * i + 2, T3 = 2 * i + 3;
    LOADB8(0); LOADA4(0, 0, 0);
    STAGE_A(1, T1, 1); LOADA4(0, 1, 1); MMA16(0, 0); BARX;
    STAGE_B(0, T2, 0); LOADA4(0, 2, 0); MMA16(1, 1); BARX;
    STAGE_B(0, T2, 1); LOADA4(0, 3, 1); MMA16(2, 0); BARX;
    STAGE_A(0, T2, 0); MMA16(3, 1); VM6; BARX;
    LOADB8(1); LOADA4(1, 0, 0);
    STAGE_A(0, T2, 1); LOADA4(1, 1, 1); MMA16(0, 0); BARX;
    STAGE_B(1, T3, 0); LOADA4(1, 2, 0); MMA16(1, 1); BARX;
    STAGE_A(1, T3, 0); LOADA4(1, 3, 1); MMA16(2, 0); BARX;
    STAGE_B(1, T3, 1); MMA16(3, 1); VM6; BARX;
  }
  {                                               // peeled final iteration
    const int TL_ = (K >> 6) - 1;
    LOADB8(0); LOADA4(0, 0, 0);
    STAGE_A(1, TL_, 1); LOADA4(0, 1, 1); MMA16(0, 0); BARX;
    LOADA4(0, 2, 0); MMA16(1, 1); BARX;
    LOADA4(0, 3, 1); MMA16(2, 0); BARX;
    MMA16(3, 1); VM0; BARX;
    LOADB8(1); LOADA4(1, 0, 0);
    LOADA4(1, 1, 1); MMA16(0, 0); BARX;
    LOADA4(1, 2, 0); MMA16(1, 1); BARX;
    LOADA4(1, 3, 1); MMA16(2, 0); BARX;
    MMA16(3, 1);
  }

  if constexpr (MODE == 0) {
    // plain epilogue: fp32 C-write (row = 4*(lane>>4)+reg, col = lane&15)
#pragma unroll
    for (int fi = 0; fi < 8; ++fi)
#pragma unroll
      for (int nf = 0; nf < 4; ++nf)
#pragma unroll
        for (int r = 0; r < 4; ++r) {
          int row = m0 + wr * 128 + fi * 16 + 4 * g + r;
          int col = n0 + wc * 64 + nf * 16 + t;
          Cv[(size_t)row * N + col] = acc[fi][nf][r];
        }
  } else {
    // fused QKV epilogue
    u16* TL = (u16*)LDSBUF;                       // [256][TLS]
    __syncthreads();                              // all LDS reads of K-loop done
#pragma unroll
    for (int fi = 0; fi < 8; ++fi)
#pragma unroll
      for (int nf = 0; nf < 4; ++nf)
#pragma unroll
        for (int r = 0; r < 4; ++r)
          TL[(wr * 128 + fi * 16 + 4 * g + r) * TLS + wc * 64 + nf * 16 + t] =
              f2bf(acc[fi][nf][r]);
    __syncthreads();

    if (n0 < (Hsz + KVsz) * Dsz) {
      // Q or K region: RoPE. wave processes one (row, head-half) per iter.
      const bool isQ = (n0 < Hsz * Dsz);
      const int j = lane;                         // 0..63 = pair index
      const float ifr = exp2f(-(float)j * L2_1E4_64);
#pragma unroll 1
      for (int it = 0; it < 64; ++it) {
        int combo = w * 64 + it;                  // 0..511
        int row = combo & 255;
        int hh = combo >> 8;                      // 0/1: head within tile
        int tok = m0 + row;
        int b = tok >> 11, s = tok & (Ssz - 1);
        float x1 = bf2f(TL[row * TLS + hh * 128 + j]);
        float x2 = bf2f(TL[row * TLS + hh * 128 + 64 + j]);
        float p = (float)pos[tok];
        float ang = p * ifr;
        float sn, cs;
        __sincosf(ang, &sn, &cs);
        float o1 = x1 * cs - x2 * sn;
        float o2 = x2 * cs + x1 * sn;
        u16* o;
        if (isQ) {
          int h = (n0 >> 7) + hh;
          o = Qr + ((size_t)(b * Hsz + h) * Ssz + s) * Dsz;
          o1 *= QSCALE; o2 *= QSCALE;
        } else {
          int kvh = ((n0 - Hsz * Dsz) >> 7) + hh;
          o = Kr + ((size_t)(b * KVsz + kvh) * Ssz + s) * Dsz;
        }
        o[j] = f2bf(o1); o[j + 64] = f2bf(o2);
      }
    } else {
      // V region: transposed write Vt[bk][d][s]; wave per d-col, lane per 4-tok
      const int dbase = n0 - (Hsz + KVsz) * Dsz;  // 0..1023
#pragma unroll 1
      for (int it = 0; it < 32; ++it) {
        int col = w * 32 + it;                    // 0..255
        int dg = dbase + col;
        int kvh = dg >> 7, d = dg & 127;
        int tok0 = m0 + 4 * lane;
        int b = tok0 >> 11, s0 = tok0 & (Ssz - 1);
        u16x4 v4;
#pragma unroll
        for (int i2 = 0; i2 < 4; ++i2)
          v4[i2] = TL[(4 * lane + i2) * TLS + col];
        *(u16x4*)(Vt + ((size_t)(b * KVsz + kvh) * Dsz + d) * Ssz + s0) = v4;
      }
    }
  }
}

// ---------------- flash attention: 8-wave swapped-QK^T 32x32 ----------------
// r10: register-capped at 1 block/CU (152 combined V+AGPR) -> per-wave diet:
//  * koff/voff LDS read offsets precomputed (statically-indexed regs, rule 20);
//    two-tile loop body with compile-time buf so +-16384 folds into ds_read imm
//  * P-exchange via v_permlane32_swap_b32 (T12): one swap of (W[r2e],W[r2e+1])
//    yields BOTH fw[c] (lo:own r2e, hi:partner r2e+1) and fw[c+2] -> replaces
//    16 ds_bpermute + 16 cndmask with 8 swaps, deletes X[] array
//  * tree max/sum reductions (depth 32 -> 5); compiler cvt_pk bf16 packing
__global__ __launch_bounds__(512, 1) void k_attn(const u16* __restrict__ Qr,
                                                 const u16* __restrict__ Kr,
                                                 const u16* __restrict__ Vt,
                                                 u16* __restrict__ AO) {
  __shared__ __align__(16) u16 Kl[2][64 * 128];  // [k][d] swizzled
  __shared__ __align__(16) u16 Vl[2][128 * 64];  // [d][k] swizzled
  const int tid = threadIdx.x;
  const int w = tid >> 6, lane = tid & 63;
  const int q = lane & 31, hi = lane >> 5;
  const int bh = blockIdx.y;
  const int b = bh >> 5, h = bh & 31;
  const int kvh = h >> 2;                        // GQA: H/KV = 4
  const int bxr = gridDim.x - 1 - blockIdx.x;    // longest blocks first
  const int q0 = bxr * 256;
  const int qw = q0 + w * 32;
  const int ntiles = 4 * bxr + 4;                // always even
  const int qg = qw + q;

  const u16* Qb = Qr + ((size_t)bh * Ssz + qw + q) * Dsz + hi * 8;
  bf16x8 qf[8];
#pragma unroll
  for (int ds = 0; ds < 8; ++ds)
    qf[ds] = __builtin_bit_cast(bf16x8, *(const u16x8*)(Qb + ds * 16));

  f32x16 oacc[4];
#pragma unroll
  for (int dt = 0; dt < 4; ++dt)
#pragma unroll
    for (int r = 0; r < 16; ++r) oacc[dt][r] = 0.f;
  float mr = -1e30f, lr = 0.f;

  // loop-invariant LDS read byte-offsets (statically indexed -> registers)
  const int xq = (q & 7) << 4;
  int koff[8][2], voff[4][4];
#pragma unroll
  for (int ds = 0; ds < 8; ++ds) {
    int c = (ds * 32 + hi * 16) ^ xq;
    koff[ds][0] = q * 256 + c;
    koff[ds][1] = (32 + q) * 256 + c;
  }
#pragma unroll
  for (int ks = 0; ks < 4; ++ks) {
    int c = (ks * 32 + hi * 16) ^ xq;
#pragma unroll
    for (int dt = 0; dt < 4; ++dt)
      voff[ks][dt] = (dt * 32 + q) * 128 + c;
  }

  const char* Kbase = (const char*)(Kr + (size_t)(b * KVsz + kvh) * Ssz * Dsz);
  const char* Vbase = (const char*)(Vt + (size_t)(b * KVsz + kvh) * Dsz * Ssz);

  auto STAGE = [&](int bu, int kt2) {
    const char* Kb = Kbase + (size_t)kt2 * (64 * 256);
    const char* Vb = Vbase + (size_t)kt2 * 128;   // 64 cols * 2B
#pragma unroll
    for (int j = 0; j < 2; ++j) {
      int flat = j * 512 + tid;
      int row = flat >> 4, colb = ((flat & 15) * 16) ^ ((row & 7) << 4);
      GLDS(Kb + (size_t)row * 256 + colb, (char*)&Kl[bu][0] + flat * 16);
    }
#pragma unroll
    for (int j = 0; j < 2; ++j) {
      int flat = j * 512 + tid;
      int row = flat >> 3, colb = ((flat & 7) * 16) ^ ((row & 7) << 4);
      GLDS(Vb + (size_t)row * (Ssz * 2) + colb, (char*)&Vl[bu][0] + flat * 16);
    }
  };

  STAGE(0, 0);
  __syncthreads();

  auto TILE = [&](int bufc, int kt) {
    const int k0 = kt * 64;
    if (kt + 1 < ntiles) STAGE(bufc ^ 1, kt + 1);  // prefetch overlaps compute

    if (k0 <= qw + 31) {                           // wave participates
      const char* Kb = (const char*)&Kl[bufc][0];
      const char* Vb = (const char*)&Vl[bufc][0];
      f32x16 pa0, pa1;
#pragma unroll
      for (int r = 0; r < 16; ++r) { pa0[r] = 0.f; pa1[r] = 0.f; }
      __builtin_amdgcn_s_setprio(1);
#pragma unroll
      for (int ds = 0; ds < 8; ++ds) {
        bf16x8 kf0 = __builtin_bit_cast(bf16x8, *(const u16x8*)(Kb + koff[ds][0]));
        pa0 = __builtin_amdgcn_mfma_f32_32x32x16_bf16(kf0, qf[ds], pa0, 0, 0, 0);
        bf16x8 kf1 = __builtin_bit_cast(bf16x8, *(const u16x8*)(Kb + koff[ds][1]));
        pa1 = __builtin_amdgcn_mfma_f32_32x32x16_bf16(kf1, qf[ds], pa1, 0, 0, 0);
      }
      __builtin_amdgcn_s_setprio(0);

      if (k0 + 63 > qw) {                          // causal mask (tail tiles)
#pragma unroll
        for (int reg = 0; reg < 16; ++reg) {
          const int kb = (reg & 3) + 8 * (reg >> 2) + 4 * hi;
          if (k0 + kb > qg)      pa0[reg] = -1e30f;
          if (k0 + 32 + kb > qg) pa1[reg] = -1e30f;
        }
      }
      // max: pairwise tree (depth 5) + cross-half
      float tmx[16];
#pragma unroll
      for (int i = 0; i < 16; ++i) tmx[i] = fmaxf(pa0[i], pa1[i]);
#pragma unroll
      for (int s = 8; s > 0; s >>= 1)
#pragma unroll
        for (int i = 0; i < s; ++i) tmx[i] = fmaxf(tmx[i], tmx[i + s]);
      const float mx = fmaxf(tmx[0], __shfl_xor(tmx[0], 32, 64));
      if (!__all(mx <= mr + 4.0f)) {               // T13 defer-max
        const float mnew = fmaxf(mr, mx);
        const float corr = exp2f(mr - mnew);
        lr *= corr;
#pragma unroll
        for (int dt = 0; dt < 4; ++dt)
#pragma unroll
          for (int reg = 0; reg < 16; ++reg) oacc[dt][reg] *= corr;
        mr = mnew;
      }
      // exp2 + sum tree
      float su[16];
#pragma unroll
      for (int reg = 0; reg < 16; ++reg) {
        pa0[reg] = exp2f(pa0[reg] - mr);
        pa1[reg] = exp2f(pa1[reg] - mr);
        su[reg] = pa0[reg] + pa1[reg];
      }
#pragma unroll
      for (int s = 8; s > 0; s >>= 1)
#pragma unroll
        for (int i = 0; i < s; ++i) su[i] += su[i + s];
      lr += su[0] + __shfl_xor(su[0], 32, 64);

      // pack P pairs (k = 8*r2 + 4*hi + 2*c + 32*T)
      uint32_t W0[4][2], W1[4][2];
#pragma unroll
      for (int r2 = 0; r2 < 4; ++r2)
#pragma unroll
        for (int c = 0; c < 2; ++c) {
          W0[r2][c] = packc(pa0[4 * r2 + 2 * c], pa0[4 * r2 + 2 * c + 1]);
          W1[r2][c] = packc(pa1[4 * r2 + 2 * c], pa1[4 * r2 + 2 * c + 1]);
        }

      __builtin_amdgcn_s_setprio(1);
#pragma unroll
      for (int ks = 0; ks < 4; ++ks) {
        const int T = ks >> 1, r2e = 2 * (ks & 1);
        uint32_t a0 = T ? W1[r2e][0]     : W0[r2e][0];
        uint32_t a1 = T ? W1[r2e][1]     : W0[r2e][1];
        uint32_t b0 = T ? W1[r2e + 1][0] : W0[r2e + 1][0];
        uint32_t b1 = T ? W1[r2e + 1][1] : W0[r2e + 1][1];
        // swap a.hi-lanes <-> b.lo-lanes: a := fw[c] (lo: own r2e, hi: partner
        // r2e+1), b := fw[c+2] (lo: partner r2e, hi: own r2e+1)
        asm("v_permlane32_swap_b32 %0, %1" : "+v"(a0), "+v"(b0));
        asm("v_permlane32_swap_b32 %0, %1" : "+v"(a1), "+v"(b1));
        u32x4 fw; fw[0] = a0; fw[1] = a1; fw[2] = b0; fw[3] = b1;
        bf16x8 pf = __builtin_bit_cast(bf16x8, fw);
#pragma unroll
        for (int dt = 0; dt < 4; ++dt) {
          bf16x8 vf = __builtin_bit_cast(bf16x8, *(const u16x8*)(Vb + voff[ks][dt]));
          oacc[dt] = __builtin_amdgcn_mfma_f32_32x32x16_bf16(vf, pf, oacc[dt], 0, 0, 0);
        }
      }
      __builtin_amdgcn_s_setprio(0);
    }
    __syncthreads();                               // drains vmcnt: next buf ready
  };

  for (int kt = 0; kt < ntiles; kt += 2) {         // ntiles % 2 == 0 always
    TILE(0, kt);
    TILE(1, kt + 1);
  }

  const float inv = 1.f / lr;
  u16* Ob = AO + ((size_t)(b * Ssz) + qw + q) * HIDsz + h * Dsz + hi * 4;
#pragma unroll
  for (int dt = 0; dt < 4; ++dt)
#pragma unroll
    for (int r2 = 0; r2 < 4; ++r2) {
      u16x4 o4;
#pragma unroll
      for (int j = 0; j < 4; ++j) o4[j] = f2bf(oacc[dt][4 * r2 + j] * inv);
      *(u16x4*)(Ob + dt * 32 + r2 * 8) = o4;
    }
}

// ---------------- host ----------------
extern "C" void kernel_launch(void* const* d_in, const int* in_sizes, int n_in,
                              void* d_out, int out_size, void* d_ws, size_t ws_size,
                              hipStream_t stream) {
  (void)in_sizes; (void)n_in; (void)out_size;
  const float* hs   = (const float*)d_in[0];
  const int*   pos  = (const int*)d_in[1];
  const float* Wqkv = (const float*)d_in[2];
  const float* Wo   = (const float*)d_in[3];

  char* ws = (char*)d_ws;
  const size_t SZ_XBF = (size_t)4096 * 4096 * 2;   // also reused for AO
  const size_t SZ_WQ  = (size_t)6144 * 4096 * 2;
  const size_t SZ_WO  = (size_t)4096 * 4096 * 2;
  const size_t SZ_QR  = (size_t)Bsz * Hsz * Ssz * Dsz * 2;
  const size_t SZ_KR  = (size_t)Bsz * KVsz * Ssz * Dsz * 2;
  const size_t SZ_VT  = SZ_KR;

  size_t off = 0;
  u16*   Xbf   = (u16*)(ws + off);  off += SZ_XBF;
  u16*   Wq_bf = (u16*)(ws + off);  off += SZ_WQ;
  u16*   Wo_bf = (u16*)(ws + off);  off += SZ_WO;
  u16*   Qr    = (u16*)(ws + off);  off += SZ_QR;
  u16*   Kr    = (u16*)(ws + off);  off += SZ_KR;
  u16*   Vt    = (u16*)(ws + off);  off += SZ_VT;
  u16*   AO    = Xbf;                               // alias (Xbf dead after gemm1)
  if (ws_size < off) return;                        // fail loudly

  // 1. fp32 -> bf16 conversions (single launch)
  k_cvt3<<<(N4_HS + N4_WQ + N4_WO + 255) / 256, 256, 0, stream>>>(
      hs, Wqkv, Wo, Xbf, Wq_bf, Wo_bf);

  // 2. QKV projection fused with RoPE + V-transpose -> Qr, Kr, Vt
  k_gemm256<1><<<dim3((NQKV / 256) * ((Bsz * Ssz) / 256)), 512, 0, stream>>>(
      Xbf, Wq_bf, nullptr, pos, Qr, Kr, Vt, Bsz * Ssz, NQKV, HIDsz);

  // 3. causal GQA attention -> AO [B,S,H*D] bf16
  k_attn<<<dim3(Ssz / 256, Bsz * Hsz), 512, 0, stream>>>(Qr, Kr, Vt, AO);

  // 4. o_proj: [4096,4096] x [4096,4096]^T -> d_out fp32
  k_gemm256<0><<<dim3((HIDsz / 256) * ((Bsz * Ssz) / 256)), 512, 0, stream>>>(
      AO, Wo_bf, (float*)d_out, nullptr, nullptr, nullptr, nullptr,
      Bsz * Ssz, HIDsz, HIDsz);
}

// Round 11
// 526.666 us; speedup vs baseline: 1.2897x; 1.0284x over previous
//
#include <hip/hip_runtime.h>
#include <stdint.h>
#include <stddef.h>

#define Bsz   2
#define Ssz   2048
#define HIDsz 4096
#define Hsz   32
#define KVsz  8
#define Dsz   128
#define NQKV  6144                     // (H+2KV)*D
// Q scale = 1/sqrt(128) * log2(e): softmax computed base-2 (exp2 is the HW op)
#define QSCALE 0.12752057463f
#define L2_1E4_64 0.20762050595f       // log2(10000)/64

typedef __bf16 bf16x8 __attribute__((ext_vector_type(8)));
typedef __bf16 bf16x2 __attribute__((ext_vector_type(2)));
typedef float  f32x4  __attribute__((ext_vector_type(4)));
typedef float  f32x16 __attribute__((ext_vector_type(16)));
typedef unsigned short u16;
typedef u16 u16x4 __attribute__((ext_vector_type(4)));
typedef u16 u16x8 __attribute__((ext_vector_type(8)));
typedef uint32_t u32x4 __attribute__((ext_vector_type(4)));

__device__ __forceinline__ u16 f2bf(float f) {
  uint32_t u = __builtin_bit_cast(uint32_t, f);
  u = (u + 0x7FFFu + ((u >> 16) & 1u)) >> 16;   // RNE
  return (u16)u;
}
__device__ __forceinline__ float bf2f(u16 h) {
  return __builtin_bit_cast(float, (uint32_t)h << 16);
}
// pair pack via compiler (emits v_cvt_pk_bf16_f32)
__device__ __forceinline__ uint32_t packc(float lo, float hi_) {
  bf16x2 t;
  t[0] = (__bf16)lo; t[1] = (__bf16)hi_;
  return __builtin_bit_cast(uint32_t, t);
}

// global -> LDS async copy, 16B per lane; LDS dest = wave-uniform base + lane*16
#define GLDS(gp, lp) __builtin_amdgcn_global_load_lds( \
    (__attribute__((address_space(1))) void*)(void*)(gp), \
    (__attribute__((address_space(3))) void*)(lp), 16, 0, 0)

// ---------------- fused fp32->bf16 conversion (one launch, 3 tensors) -------
#define N4_HS  ((Bsz * Ssz * HIDsz) / 4)
#define N4_WQ  ((NQKV * HIDsz) / 4)
#define N4_WO  ((HIDsz * HIDsz) / 4)
__global__ __launch_bounds__(256) void k_cvt3(const float* __restrict__ hs,
                                              const float* __restrict__ wqkv,
                                              const float* __restrict__ wo,
                                              u16* __restrict__ xbf,
                                              u16* __restrict__ wqbf,
                                              u16* __restrict__ wobf) {
  int i = blockIdx.x * 256 + threadIdx.x;
  const float* src; u16* dst; int off;
  if (i < N4_HS)                   { src = hs;   dst = xbf;  off = i; }
  else if (i < N4_HS + N4_WQ)      { src = wqkv; dst = wqbf; off = i - N4_HS; }
  else if (i < N4_HS + N4_WQ + N4_WO) { src = wo; dst = wobf; off = i - N4_HS - N4_WQ; }
  else return;
  float4 v = ((const float4*)src)[off];
  u16x4 o;
  o.x = f2bf(v.x); o.y = f2bf(v.y); o.z = f2bf(v.z); o.w = f2bf(v.w);
  ((u16x4*)dst)[off] = o;
}

// ============ 256x256 8-phase GEMM: C[M][N] = A[M][K] * B[N][K]^T ============
// MODE 0: plain fp32 C-write (o_proj), grid M/256 x N/256, stride N.
// MODE 1: Q-region of qkv-proj (bn 0..15, 256 blocks): fused RoPE-Q epilogue.
// MODE 2: K/V-region K-split partials: 128 tiles (bn 16..23) x 2 K-halves =
//   256 blocks. h = swz>>7 selects K window [h*2048, h*2048+2048); A/B bases
//   pre-offset h*2048 elements (row stride stays K_ld); fp32 out to
//   Cv + h*4096*2048, strip layout [4096][2048], col base n0-4096.
// Schedule ledger holds for K_len=2048: NI=15, peel tile 31 odd -> buf1,
// matching STAGE_A(1,TL_,1); vmcnt(6) points unchanged.

#define BARX do { asm volatile("" ::: "memory"); __builtin_amdgcn_s_barrier(); \
                  asm volatile("" ::: "memory"); } while (0)
#define VM6  asm volatile("s_waitcnt vmcnt(6)" ::: "memory")
#define VM0  asm volatile("s_waitcnt vmcnt(0)" ::: "memory")

#define LOADA4(P_, Q_, F_) do {                                               \
    afr[F_][0] = LDA(P_, Q_, 0, 0); afr[F_][1] = LDA(P_, Q_, 0, 1);           \
    afr[F_][2] = LDA(P_, Q_, 1, 0); afr[F_][3] = LDA(P_, Q_, 1, 1);           \
  } while (0)

#define LOADB8(P_) do {                                                       \
    _Pragma("unroll") for (int nf = 0; nf < 4; ++nf) {                        \
      bfr[nf][0] = LDB(P_, nf, 0); bfr[nf][1] = LDB(P_, nf, 1); }             \
  } while (0)

#define MMA16(Q_, F_) do {                                                    \
    __builtin_amdgcn_s_setprio(1);                                            \
    _Pragma("unroll") for (int nf = 0; nf < 4; ++nf) {                        \
      acc[(Q_)*2][nf]   = __builtin_amdgcn_mfma_f32_16x16x32_bf16(afr[F_][0], bfr[nf][0], acc[(Q_)*2][nf],   0,0,0); \
      acc[(Q_)*2+1][nf] = __builtin_amdgcn_mfma_f32_16x16x32_bf16(afr[F_][2], bfr[nf][0], acc[(Q_)*2+1][nf], 0,0,0); \
    }                                                                         \
    _Pragma("unroll") for (int nf = 0; nf < 4; ++nf) {                        \
      acc[(Q_)*2][nf]   = __builtin_amdgcn_mfma_f32_16x16x32_bf16(afr[F_][1], bfr[nf][1], acc[(Q_)*2][nf],   0,0,0); \
      acc[(Q_)*2+1][nf] = __builtin_amdgcn_mfma_f32_16x16x32_bf16(afr[F_][3], bfr[nf][1], acc[(Q_)*2+1][nf], 0,0,0); \
    }                                                                         \
    __builtin_amdgcn_s_setprio(0);                                            \
  } while (0)

#define TLS 258                         // MODE1 epilogue LDS tile stride (u16)

template <int MODE>
__global__ __launch_bounds__(512, 1) void k_gemm256(const u16* __restrict__ A,
                                                    const u16* __restrict__ Bm,
                                                    float* __restrict__ Cv,
                                                    const int* __restrict__ pos,
                                                    u16* __restrict__ Qr,
                                                    int M, int N, int K_ld,
                                                    int K_len) {
  constexpr int LDS_BYTES = (MODE == 1) ? (256 * TLS * 2) : (4 * 256 * 64 * 2);
  __shared__ __align__(16) char LDSBUF[LDS_BYTES];
  u16* SA0 = (u16*)LDSBUF;                        // SA[2][256*64]
  u16* SB0 = (u16*)(LDSBUF + 65536);              // SB[2][256*64]
  const int tid = threadIdx.x;
  const int w = tid >> 6, lane = tid & 63;
  const int g = lane >> 4, t = lane & 15;
  const int wr = w >> 2, wc = w & 3;
  const int cpx = gridDim.x >> 3;                 // grid %8 == 0 (always 256)
  const int swz = (blockIdx.x & 7) * cpx + (blockIdx.x >> 3);

  int bm, bn;
  const u16 *Au = A, *Bu = Bm;
  float* Cu = Cv;
  if constexpr (MODE == 2) {
    const int t2 = swz & 127, h2 = swz >> 7;
    bm = t2 & 15; bn = 16 + (t2 >> 4);
    Au = A + h2 * 2048; Bu = Bm + h2 * 2048;
    Cu = Cv + (size_t)h2 * 4096 * 2048;
  } else {
    const int MBt = M >> 8;
    bm = swz % MBt; bn = swz / MBt;               // column-major tile order
  }
  const int m0 = bm << 8, n0 = bn << 8;

  const char* Ab = (const char*)Au;
  const char* Bb = (const char*)Bu;
  const size_t rowK = (size_t)K_ld * 2;           // bytes per input row
  const int srcx = ((lane & 7) ^ (lane >> 3)) << 4;  // pre-swizzled src col
  const int l3 = lane >> 3;
  const int tx = (t & 7) << 4;                    // read-side XOR (bytes)

  auto SToff = [&](int h, int j) -> int {
    int ii = w * 2 + j;
    return (ii < 8) ? (h * 64 + ii * 8) : (128 + h * 64 + (ii - 8) * 8);
  };
  auto STAGE_A = [&](int p, int T, int h) {
#pragma unroll
    for (int j = 0; j < 2; ++j) {
      int rb = SToff(h, j);
      GLDS(Ab + (size_t)(m0 + rb + l3) * rowK + (size_t)T * 128 + srcx,
           &SA0[p * 16384 + rb * 64]);
    }
  };
  auto STAGE_B = [&](int p, int T, int h) {
#pragma unroll
    for (int j = 0; j < 2; ++j) {
      int rb = SToff(h, j);
      GLDS(Bb + (size_t)(n0 + rb + l3) * rowK + (size_t)T * 128 + srcx,
           &SB0[p * 16384 + rb * 64]);
    }
  };
  auto LDA = [&](int p, int q, int fr, int kk) -> bf16x8 {
    int ar = wr * 128 + q * 32 + fr * 16 + t;
    const char* ptr = (const char*)&SA0[p * 16384] + ar * 128 + ((kk * 64 + 16 * g) ^ tx);
    return __builtin_bit_cast(bf16x8, *(const u16x8*)ptr);
  };
  auto LDB = [&](int p, int nf, int kk) -> bf16x8 {
    int br = wc * 64 + nf * 16 + t;
    const char* ptr = (const char*)&SB0[p * 16384] + br * 128 + ((kk * 64 + 16 * g) ^ tx);
    return __builtin_bit_cast(bf16x8, *(const u16x8*)ptr);
  };

  f32x4 acc[8][4];
#pragma unroll
  for (int i = 0; i < 8; ++i)
#pragma unroll
    for (int j = 0; j < 4; ++j) acc[i][j] = (f32x4){0.f, 0.f, 0.f, 0.f};
  bf16x8 bfr[4][2];
  bf16x8 afr[2][4];

  // prologue: T0 complete (8 loads) + T1.{A0,B0,B1} (6 loads)
  STAGE_A(0, 0, 0); STAGE_B(0, 0, 0); STAGE_A(0, 0, 1); STAGE_B(0, 0, 1);
  STAGE_A(1, 1, 0); STAGE_B(1, 1, 0); STAGE_B(1, 1, 1);
  VM6;                                            // T0 landed
  __builtin_amdgcn_s_barrier();

  const int NI = (K_len >> 7) - 1;
  for (int i = 0; i < NI; ++i) {
    const int T1 = 2 * i + 1, T2 = 2 * i + 2, T3 = 2 * i + 3;
    LOADB8(0); LOADA4(0, 0, 0);
    STAGE_A(1, T1, 1); LOADA4(0, 1, 1); MMA16(0, 0); BARX;
    STAGE_B(0, T2, 0); LOADA4(0, 2, 0); MMA16(1, 1); BARX;
    STAGE_B(0, T2, 1); LOADA4(0, 3, 1); MMA16(2, 0); BARX;
    STAGE_A(0, T2, 0); MMA16(3, 1); VM6; BARX;
    LOADB8(1); LOADA4(1, 0, 0);
    STAGE_A(0, T2, 1); LOADA4(1, 1, 1); MMA16(0, 0); BARX;
    STAGE_B(1, T3, 0); LOADA4(1, 2, 0); MMA16(1, 1); BARX;
    STAGE_A(1, T3, 0); LOADA4(1, 3, 1); MMA16(2, 0); BARX;
    STAGE_B(1, T3, 1); MMA16(3, 1); VM6; BARX;
  }
  {                                               // peeled final iteration
    const int TL_ = (K_len >> 6) - 1;
    LOADB8(0); LOADA4(0, 0, 0);
    STAGE_A(1, TL_, 1); LOADA4(0, 1, 1); MMA16(0, 0); BARX;
    LOADA4(0, 2, 0); MMA16(1, 1); BARX;
    LOADA4(0, 3, 1); MMA16(2, 0); BARX;
    MMA16(3, 1); VM0; BARX;
    LOADB8(1); LOADA4(1, 0, 0);
    LOADA4(1, 1, 1); MMA16(0, 0); BARX;
    LOADA4(1, 2, 0); MMA16(1, 1); BARX;
    LOADA4(1, 3, 1); MMA16(2, 0); BARX;
    MMA16(3, 1);
  }

  if constexpr (MODE == 0 || MODE == 2) {
    // fp32 C-write (row = 4*(lane>>4)+reg, col = lane&15)
    const int cstride = (MODE == 0) ? N : 2048;
    const int cbase   = (MODE == 0) ? n0 : (n0 - 4096);
#pragma unroll
    for (int fi = 0; fi < 8; ++fi)
#pragma unroll
      for (int nf = 0; nf < 4; ++nf)
#pragma unroll
        for (int r = 0; r < 4; ++r) {
          int row = m0 + wr * 128 + fi * 16 + 4 * g + r;
          int col = cbase + wc * 64 + nf * 16 + t;
          Cu[(size_t)row * cstride + col] = acc[fi][nf][r];
        }
  } else {
    // MODE 1: fused RoPE-Q epilogue (n0 < 4096 always)
    u16* TL = (u16*)LDSBUF;                       // [256][TLS]
    __syncthreads();                              // all LDS reads of K-loop done
#pragma unroll
    for (int fi = 0; fi < 8; ++fi)
#pragma unroll
      for (int nf = 0; nf < 4; ++nf)
#pragma unroll
        for (int r = 0; r < 4; ++r)
          TL[(wr * 128 + fi * 16 + 4 * g + r) * TLS + wc * 64 + nf * 16 + t] =
              f2bf(acc[fi][nf][r]);
    __syncthreads();

    const int j = lane;                           // 0..63 = pair index
    const float ifr = exp2f(-(float)j * L2_1E4_64);
#pragma unroll 1
    for (int it = 0; it < 64; ++it) {
      int combo = w * 64 + it;                    // 0..511
      int row = combo & 255;
      int hh = combo >> 8;                        // 0/1: head within tile
      int tok = m0 + row;
      int b = tok >> 11, s = tok & (Ssz - 1);
      float x1 = bf2f(TL[row * TLS + hh * 128 + j]);
      float x2 = bf2f(TL[row * TLS + hh * 128 + 64 + j]);
      float p = (float)pos[tok];
      float ang = p * ifr;
      float sn, cs;
      __sincosf(ang, &sn, &cs);
      float o1 = (x1 * cs - x2 * sn) * QSCALE;
      float o2 = (x2 * cs + x1 * sn) * QSCALE;
      int h = (n0 >> 7) + hh;
      u16* o = Qr + ((size_t)(b * Hsz + h) * Ssz + s) * Dsz;
      o[j] = f2bf(o1); o[j + 64] = f2bf(o2);
    }
  }
}

// --------- K-region: sum K-split partials + RoPE -> Kr[b][kvh][s][d] --------
__global__ __launch_bounds__(256) void k_ropeK2(const float* __restrict__ Cp,
                                                const int* __restrict__ pos,
                                                u16* __restrict__ Kr) {
  int idx = blockIdx.x * 256 + threadIdx.x;       // B*S*KV*64
  if (idx >= Bsz * Ssz * KVsz * 64) return;
  const size_t OFF2 = (size_t)4096 * 2048;
  int j = idx & 63;
  int kvh = (idx >> 6) & 7;
  int bs = idx >> 9;                              // 0..4095
  size_t p0 = (size_t)bs * 2048 + kvh * 128 + j;
  float x1 = Cp[p0] + Cp[p0 + OFF2];
  float x2 = Cp[p0 + 64] + Cp[p0 + 64 + OFF2];
  float p = (float)pos[bs];
  float ang = p * exp2f(-(float)j * L2_1E4_64);
  float sn, cs;
  __sincosf(ang, &sn, &cs);
  int b = bs >> 11, sidx = bs & (Ssz - 1);
  u16* o = Kr + ((size_t)(b * KVsz + kvh) * Ssz + sidx) * Dsz;
  o[j] = f2bf(x1 * cs - x2 * sn);
  o[j + 64] = f2bf(x2 * cs + x1 * sn);
}

// --------- V-region: sum partials + LDS transpose -> Vt[bk][d][s] -----------
__global__ __launch_bounds__(256) void k_vtrans2(const float* __restrict__ Cp,
                                                 u16* __restrict__ Vt) {
  __shared__ __align__(16) u16 Tl[64 * 72];
  const int tid = threadIdx.x;
  const int bk = blockIdx.y;                      // b*KV + kvh
  const int s0 = (blockIdx.x >> 1) * 64;
  const int d0 = (blockIdx.x & 1) * 64;
  const int b = bk >> 3, kvh = bk & 7;
  const size_t OFF2 = (size_t)4096 * 2048;
  // strip row = b*2048 + s0 + r ; strip col = 1024 + kvh*128 + d0 + c
  const size_t base = (size_t)(b * Ssz + s0) * 2048 + 1024 + kvh * 128 + d0;
#pragma unroll
  for (int p = 0; p < 2; ++p) {
    int cid = p * 256 + tid;
    int r = cid >> 3, co = cid & 7;
    int chunk = co ^ ((r >> 3) & 7);
    const float* s1 = Cp + base + (size_t)r * 2048 + co * 8;
    u16x8 v;
#pragma unroll
    for (int e = 0; e < 8; ++e) v[e] = f2bf(s1[e] + s1[OFF2 + e]);
    *(u16x8*)((char*)Tl + r * 144 + chunk * 16) = v;
  }
  __syncthreads();
#pragma unroll
  for (int p = 0; p < 2; ++p) {
    int cid = p * 256 + tid;
    int dr = cid >> 3, c = cid & 7;
    u16x8 v;
#pragma unroll
    for (int j = 0; j < 8; ++j) {
      int s = 8 * c + j;
      v[j] = *(const u16*)((char*)Tl + s * 144 + (((dr >> 3) ^ c) * 16) + (dr & 7) * 2);
    }
    *(u16x8*)(Vt + ((size_t)bk * Dsz + d0 + dr) * Ssz + s0 + 8 * c) = v;
  }
}

// ---------------- flash attention: 8-wave swapped-QK^T 32x32 ----------------
__global__ __launch_bounds__(512, 1) void k_attn(const u16* __restrict__ Qr,
                                                 const u16* __restrict__ Kr,
                                                 const u16* __restrict__ Vt,
                                                 u16* __restrict__ AO) {
  __shared__ __align__(16) u16 Kl[2][64 * 128];  // [k][d] swizzled
  __shared__ __align__(16) u16 Vl[2][128 * 64];  // [d][k] swizzled
  const int tid = threadIdx.x;
  const int w = tid >> 6, lane = tid & 63;
  const int q = lane & 31, hi = lane >> 5;
  const int bh = blockIdx.y;
  const int b = bh >> 5, h = bh & 31;
  const int kvh = h >> 2;                        // GQA: H/KV = 4
  const int bxr = gridDim.x - 1 - blockIdx.x;    // longest blocks first
  const int q0 = bxr * 256;
  const int qw = q0 + w * 32;
  const int ntiles = 4 * bxr + 4;                // always even
  const int qg = qw + q;

  const u16* Qb = Qr + ((size_t)bh * Ssz + qw + q) * Dsz + hi * 8;
  bf16x8 qf[8];
#pragma unroll
  for (int ds = 0; ds < 8; ++ds)
    qf[ds] = __builtin_bit_cast(bf16x8, *(const u16x8*)(Qb + ds * 16));

  f32x16 oacc[4];
#pragma unroll
  for (int dt = 0; dt < 4; ++dt)
#pragma unroll
    for (int r = 0; r < 16; ++r) oacc[dt][r] = 0.f;
  float mr = -1e30f, lr = 0.f;

  const int xq = (q & 7) << 4;
  int koff[8][2], voff[4][4];
#pragma unroll
  for (int ds = 0; ds < 8; ++ds) {
    int c = (ds * 32 + hi * 16) ^ xq;
    koff[ds][0] = q * 256 + c;
    koff[ds][1] = (32 + q) * 256 + c;
  }
#pragma unroll
  for (int ks = 0; ks < 4; ++ks) {
    int c = (ks * 32 + hi * 16) ^ xq;
#pragma unroll
    for (int dt = 0; dt < 4; ++dt)
      voff[ks][dt] = (dt * 32 + q) * 128 + c;
  }

  const char* Kbase = (const char*)(Kr + (size_t)(b * KVsz + kvh) * Ssz * Dsz);
  const char* Vbase = (const char*)(Vt + (size_t)(b * KVsz + kvh) * Dsz * Ssz);

  auto STAGE = [&](int bu, int kt2) {
    const char* Kb = Kbase + (size_t)kt2 * (64 * 256);
    const char* Vb = Vbase + (size_t)kt2 * 128;   // 64 cols * 2B
#pragma unroll
    for (int j = 0; j < 2; ++j) {
      int flat = j * 512 + tid;
      int row = flat >> 4, colb = ((flat & 15) * 16) ^ ((row & 7) << 4);
      GLDS(Kb + (size_t)row * 256 + colb, (char*)&Kl[bu][0] + flat * 16);
    }
#pragma unroll
    for (int j = 0; j < 2; ++j) {
      int flat = j * 512 + tid;
      int row = flat >> 3, colb = ((flat & 7) * 16) ^ ((row & 7) << 4);
      GLDS(Vb + (size_t)row * (Ssz * 2) + colb, (char*)&Vl[bu][0] + flat * 16);
    }
  };

  STAGE(0, 0);
  __syncthreads();

  auto TILE = [&](int bufc, int kt) {
    const int k0 = kt * 64;
    if (kt + 1 < ntiles) STAGE(bufc ^ 1, kt + 1);  // prefetch overlaps compute

    if (k0 <= qw + 31) {                           // wave participates
      const char* Kb = (const char*)&Kl[bufc][0];
      const char* Vb = (const char*)&Vl[bufc][0];
      f32x16 pa0, pa1;
#pragma unroll
      for (int r = 0; r < 16; ++r) { pa0[r] = 0.f; pa1[r] = 0.f; }
      __builtin_amdgcn_s_setprio(1);
#pragma unroll
      for (int ds = 0; ds < 8; ++ds) {
        bf16x8 kf0 = __builtin_bit_cast(bf16x8, *(const u16x8*)(Kb + koff[ds][0]));
        pa0 = __builtin_amdgcn_mfma_f32_32x32x16_bf16(kf0, qf[ds], pa0, 0, 0, 0);
        bf16x8 kf1 = __builtin_bit_cast(bf16x8, *(const u16x8*)(Kb + koff[ds][1]));
        pa1 = __builtin_amdgcn_mfma_f32_32x32x16_bf16(kf1, qf[ds], pa1, 0, 0, 0);
      }
      __builtin_amdgcn_s_setprio(0);

      if (k0 + 63 > qw) {                          // causal mask (tail tiles)
#pragma unroll
        for (int reg = 0; reg < 16; ++reg) {
          const int kb = (reg & 3) + 8 * (reg >> 2) + 4 * hi;
          if (k0 + kb > qg)      pa0[reg] = -1e30f;
          if (k0 + 32 + kb > qg) pa1[reg] = -1e30f;
        }
      }
      float tmx[16];
#pragma unroll
      for (int i = 0; i < 16; ++i) tmx[i] = fmaxf(pa0[i], pa1[i]);
#pragma unroll
      for (int s = 8; s > 0; s >>= 1)
#pragma unroll
        for (int i = 0; i < s; ++i) tmx[i] = fmaxf(tmx[i], tmx[i + s]);
      const float mx = fmaxf(tmx[0], __shfl_xor(tmx[0], 32, 64));
      if (!__all(mx <= mr + 4.0f)) {               // T13 defer-max
        const float mnew = fmaxf(mr, mx);
        const float corr = exp2f(mr - mnew);
        lr *= corr;
#pragma unroll
        for (int dt = 0; dt < 4; ++dt)
#pragma unroll
          for (int reg = 0; reg < 16; ++reg) oacc[dt][reg] *= corr;
        mr = mnew;
      }
      float su[16];
#pragma unroll
      for (int reg = 0; reg < 16; ++reg) {
        pa0[reg] = exp2f(pa0[reg] - mr);
        pa1[reg] = exp2f(pa1[reg] - mr);
        su[reg] = pa0[reg] + pa1[reg];
      }
#pragma unroll
      for (int s = 8; s > 0; s >>= 1)
#pragma unroll
        for (int i = 0; i < s; ++i) su[i] += su[i + s];
      lr += su[0] + __shfl_xor(su[0], 32, 64);

      uint32_t W0[4][2], W1[4][2];
#pragma unroll
      for (int r2 = 0; r2 < 4; ++r2)
#pragma unroll
        for (int c = 0; c < 2; ++c) {
          W0[r2][c] = packc(pa0[4 * r2 + 2 * c], pa0[4 * r2 + 2 * c + 1]);
          W1[r2][c] = packc(pa1[4 * r2 + 2 * c], pa1[4 * r2 + 2 * c + 1]);
        }

      __builtin_amdgcn_s_setprio(1);
#pragma unroll
      for (int ks = 0; ks < 4; ++ks) {
        const int T = ks >> 1, r2e = 2 * (ks & 1);
        uint32_t a0 = T ? W1[r2e][0]     : W0[r2e][0];
        uint32_t a1 = T ? W1[r2e][1]     : W0[r2e][1];
        uint32_t b0 = T ? W1[r2e + 1][0] : W0[r2e + 1][0];
        uint32_t b1 = T ? W1[r2e + 1][1] : W0[r2e + 1][1];
        asm("v_permlane32_swap_b32 %0, %1" : "+v"(a0), "+v"(b0));
        asm("v_permlane32_swap_b32 %0, %1" : "+v"(a1), "+v"(b1));
        u32x4 fw; fw[0] = a0; fw[1] = a1; fw[2] = b0; fw[3] = b1;
        bf16x8 pf = __builtin_bit_cast(bf16x8, fw);
#pragma unroll
        for (int dt = 0; dt < 4; ++dt) {
          bf16x8 vf = __builtin_bit_cast(bf16x8, *(const u16x8*)(Vb + voff[ks][dt]));
          oacc[dt] = __builtin_amdgcn_mfma_f32_32x32x16_bf16(vf, pf, oacc[dt], 0, 0, 0);
        }
      }
      __builtin_amdgcn_s_setprio(0);
    }
    __syncthreads();                               // drains vmcnt: next buf ready
  };

  for (int kt = 0; kt < ntiles; kt += 2) {         // ntiles % 2 == 0 always
    TILE(0, kt);
    TILE(1, kt + 1);
  }

  const float inv = 1.f / lr;
  u16* Ob = AO + ((size_t)(b * Ssz) + qw + q) * HIDsz + h * Dsz + hi * 4;
#pragma unroll
  for (int dt = 0; dt < 4; ++dt)
#pragma unroll
    for (int r2 = 0; r2 < 4; ++r2) {
      u16x4 o4;
#pragma unroll
      for (int j = 0; j < 4; ++j) o4[j] = f2bf(oacc[dt][4 * r2 + j] * inv);
      *(u16x4*)(Ob + dt * 32 + r2 * 8) = o4;
    }
}

// ---------------- host ----------------
extern "C" void kernel_launch(void* const* d_in, const int* in_sizes, int n_in,
                              void* d_out, int out_size, void* d_ws, size_t ws_size,
                              hipStream_t stream) {
  (void)in_sizes; (void)n_in; (void)out_size;
  const float* hs   = (const float*)d_in[0];
  const int*   pos  = (const int*)d_in[1];
  const float* Wqkv = (const float*)d_in[2];
  const float* Wo   = (const float*)d_in[3];

  char* ws = (char*)d_ws;
  const size_t SZ_XBF = (size_t)4096 * 4096 * 2;   // also reused for AO
  const size_t SZ_WQ  = (size_t)6144 * 4096 * 2;
  const size_t SZ_WO  = (size_t)4096 * 4096 * 2;
  const size_t SZ_QR  = (size_t)Bsz * Hsz * Ssz * Dsz * 2;
  const size_t SZ_KR  = (size_t)Bsz * KVsz * Ssz * Dsz * 2;
  const size_t SZ_VT  = SZ_KR;

  size_t off = 0;
  u16*   Xbf   = (u16*)(ws + off);  off += SZ_XBF;
  u16*   Wq_bf = (u16*)(ws + off);  off += SZ_WQ;
  u16*   Wo_bf = (u16*)(ws + off);  off += SZ_WO;
  u16*   Qr    = (u16*)(ws + off);  off += SZ_QR;
  u16*   Kr    = (u16*)(ws + off);  off += SZ_KR;
  u16*   Vt    = (u16*)(ws + off);  off += SZ_VT;
  u16*   AO    = Xbf;                               // alias (Xbf dead after gemm1)
  float* Cp    = (float*)d_out;                     // K-split partials: d_out as
                                                    // scratch (2x[4096][2048] fp32
                                                    // = 67MB exact), overwritten
                                                    // fully by gemm2 afterwards
  if (ws_size < off) return;                        // fail loudly

  // 1. fp32 -> bf16 conversions (single launch)
  k_cvt3<<<(N4_HS + N4_WQ + N4_WO + 255) / 256, 256, 0, stream>>>(
      hs, Wqkv, Wo, Xbf, Wq_bf, Wo_bf);

  // 2a. QKV projection, Q region (bn 0..15, 256 blocks, 1 clean round),
  //     fused RoPE-Q epilogue -> Qr
  k_gemm256<1><<<256, 512, 0, stream>>>(Xbf, Wq_bf, nullptr, pos, Qr,
                                        Bsz * Ssz, NQKV, HIDsz, HIDsz);

  // 2b. QKV projection, K/V region K-split partials (128 tiles x 2 halves =
  //     256 blocks, 1 clean half-round) -> Cp (= d_out scratch)
  k_gemm256<2><<<256, 512, 0, stream>>>(Xbf, Wq_bf, Cp, nullptr, nullptr,
                                        Bsz * Ssz, NQKV, HIDsz, 2048);

  // 2c. sum partials + RoPE-K -> Kr ; sum + transpose -> Vt
  k_ropeK2<<<(Bsz * Ssz * KVsz * 64) / 256, 256, 0, stream>>>(Cp, pos, Kr);
  k_vtrans2<<<dim3(64, Bsz * KVsz), 256, 0, stream>>>(Cp, Vt);

  // 3. causal GQA attention -> AO [B,S,H*D] bf16
  k_attn<<<dim3(Ssz / 256, Bsz * Hsz), 512, 0, stream>>>(Qr, Kr, Vt, AO);

  // 4. o_proj: [4096,4096] x [4096,4096]^T -> d_out fp32 (overwrites scratch)
  k_gemm256<0><<<256, 512, 0, stream>>>(AO, Wo_bf, (float*)d_out, nullptr,
                                        nullptr, Bsz * Ssz, HIDsz, HIDsz, HIDsz);
}

// Round 12
// 464.121 us; speedup vs baseline: 1.4636x; 1.1348x over previous
//
#include <hip/hip_runtime.h>
#include <stdint.h>
#include <stddef.h>

#define Bsz   2
#define Ssz   2048
#define HIDsz 4096
#define Hsz   32
#define KVsz  8
#define Dsz   128
#define NQKV  6144                     // (H+2KV)*D
// Q scale = 1/sqrt(128) * log2(e): softmax computed base-2 (exp2 is the HW op)
#define QSCALE 0.12752057463f
#define L2_1E4_64 0.20762050595f       // log2(10000)/64

typedef __bf16 bf16x8 __attribute__((ext_vector_type(8)));
typedef __bf16 bf16x2 __attribute__((ext_vector_type(2)));
typedef float  f32x4  __attribute__((ext_vector_type(4)));
typedef float  f32x16 __attribute__((ext_vector_type(16)));
typedef unsigned short u16;
typedef u16 u16x4 __attribute__((ext_vector_type(4)));
typedef u16 u16x8 __attribute__((ext_vector_type(8)));
typedef uint32_t u32x4 __attribute__((ext_vector_type(4)));

__device__ __forceinline__ u16 f2bf(float f) {
  uint32_t u = __builtin_bit_cast(uint32_t, f);
  u = (u + 0x7FFFu + ((u >> 16) & 1u)) >> 16;   // RNE
  return (u16)u;
}
__device__ __forceinline__ float bf2f(u16 h) {
  return __builtin_bit_cast(float, (uint32_t)h << 16);
}
// pair pack via compiler (emits v_cvt_pk_bf16_f32)
__device__ __forceinline__ uint32_t packc(float lo, float hi_) {
  bf16x2 t;
  t[0] = (__bf16)lo; t[1] = (__bf16)hi_;
  return __builtin_bit_cast(uint32_t, t);
}

// global -> LDS async copy, 16B per lane; LDS dest = wave-uniform base + lane*16
#define GLDS(gp, lp) __builtin_amdgcn_global_load_lds( \
    (__attribute__((address_space(1))) void*)(void*)(gp), \
    (__attribute__((address_space(3))) void*)(lp), 16, 0, 0)

// ---------------- fused fp32->bf16 conversion (one launch, 3 tensors) -------
#define N4_HS  ((Bsz * Ssz * HIDsz) / 4)
#define N4_WQ  ((NQKV * HIDsz) / 4)
#define N4_WO  ((HIDsz * HIDsz) / 4)
__global__ __launch_bounds__(256) void k_cvt3(const float* __restrict__ hs,
                                              const float* __restrict__ wqkv,
                                              const float* __restrict__ wo,
                                              u16* __restrict__ xbf,
                                              u16* __restrict__ wqbf,
                                              u16* __restrict__ wobf) {
  int i = blockIdx.x * 256 + threadIdx.x;
  const float* src; u16* dst; int off;
  if (i < N4_HS)                   { src = hs;   dst = xbf;  off = i; }
  else if (i < N4_HS + N4_WQ)      { src = wqkv; dst = wqbf; off = i - N4_HS; }
  else if (i < N4_HS + N4_WQ + N4_WO) { src = wo; dst = wobf; off = i - N4_HS - N4_WQ; }
  else return;
  float4 v = ((const float4*)src)[off];
  u16x4 o;
  o.x = f2bf(v.x); o.y = f2bf(v.y); o.z = f2bf(v.z); o.w = f2bf(v.w);
  ((u16x4*)dst)[off] = o;
}

// ============ 256x256 8-phase GEMM: C[M][N] = A[M][K] * B[N][K]^T ============
// MODE 0: plain fp32 C-write (o_proj), grid M/256 x N/256, stride N.
// MODE 1: Q-region of qkv-proj (bn 0..15, 256 blocks): fused RoPE-Q epilogue.
// MODE 2: K/V-region K-split partials: 128 tiles (bn 16..23) x 2 K-halves.

#define BARX do { asm volatile("" ::: "memory"); __builtin_amdgcn_s_barrier(); \
                  asm volatile("" ::: "memory"); } while (0)
#define VM6  asm volatile("s_waitcnt vmcnt(6)" ::: "memory")
#define VM0  asm volatile("s_waitcnt vmcnt(0)" ::: "memory")

#define LOADA4(P_, Q_, F_) do {                                               \
    afr[F_][0] = LDA(P_, Q_, 0, 0); afr[F_][1] = LDA(P_, Q_, 0, 1);           \
    afr[F_][2] = LDA(P_, Q_, 1, 0); afr[F_][3] = LDA(P_, Q_, 1, 1);           \
  } while (0)

#define LOADB8(P_) do {                                                       \
    _Pragma("unroll") for (int nf = 0; nf < 4; ++nf) {                        \
      bfr[nf][0] = LDB(P_, nf, 0); bfr[nf][1] = LDB(P_, nf, 1); }             \
  } while (0)

#define MMA16(Q_, F_) do {                                                    \
    __builtin_amdgcn_s_setprio(1);                                            \
    _Pragma("unroll") for (int nf = 0; nf < 4; ++nf) {                        \
      acc[(Q_)*2][nf]   = __builtin_amdgcn_mfma_f32_16x16x32_bf16(afr[F_][0], bfr[nf][0], acc[(Q_)*2][nf],   0,0,0); \
      acc[(Q_)*2+1][nf] = __builtin_amdgcn_mfma_f32_16x16x32_bf16(afr[F_][2], bfr[nf][0], acc[(Q_)*2+1][nf], 0,0,0); \
    }                                                                         \
    _Pragma("unroll") for (int nf = 0; nf < 4; ++nf) {                        \
      acc[(Q_)*2][nf]   = __builtin_amdgcn_mfma_f32_16x16x32_bf16(afr[F_][1], bfr[nf][1], acc[(Q_)*2][nf],   0,0,0); \
      acc[(Q_)*2+1][nf] = __builtin_amdgcn_mfma_f32_16x16x32_bf16(afr[F_][3], bfr[nf][1], acc[(Q_)*2+1][nf], 0,0,0); \
    }                                                                         \
    __builtin_amdgcn_s_setprio(0);                                            \
  } while (0)

#define TLS 258                         // MODE1 epilogue LDS tile stride (u16)

template <int MODE>
__global__ __launch_bounds__(512, 1) void k_gemm256(const u16* __restrict__ A,
                                                    const u16* __restrict__ Bm,
                                                    float* __restrict__ Cv,
                                                    const int* __restrict__ pos,
                                                    u16* __restrict__ Qr,
                                                    int M, int N, int K_ld,
                                                    int K_len) {
  constexpr int LDS_BYTES = (MODE == 1) ? (256 * TLS * 2) : (4 * 256 * 64 * 2);
  __shared__ __align__(16) char LDSBUF[LDS_BYTES];
  u16* SA0 = (u16*)LDSBUF;                        // SA[2][256*64]
  u16* SB0 = (u16*)(LDSBUF + 65536);              // SB[2][256*64]
  const int tid = threadIdx.x;
  const int w = tid >> 6, lane = tid & 63;
  const int g = lane >> 4, t = lane & 15;
  const int wr = w >> 2, wc = w & 3;
  const int cpx = gridDim.x >> 3;                 // grid %8 == 0 (always 256)
  const int swz = (blockIdx.x & 7) * cpx + (blockIdx.x >> 3);

  int bm, bn;
  const u16 *Au = A, *Bu = Bm;
  float* Cu = Cv;
  if constexpr (MODE == 2) {
    const int t2 = swz & 127, h2 = swz >> 7;
    bm = t2 & 15; bn = 16 + (t2 >> 4);
    Au = A + h2 * 2048; Bu = Bm + h2 * 2048;
    Cu = Cv + (size_t)h2 * 4096 * 2048;
  } else {
    const int MBt = M >> 8;
    bm = swz % MBt; bn = swz / MBt;               // column-major tile order
  }
  const int m0 = bm << 8, n0 = bn << 8;

  const char* Ab = (const char*)Au;
  const char* Bb = (const char*)Bu;
  const size_t rowK = (size_t)K_ld * 2;           // bytes per input row
  const int srcx = ((lane & 7) ^ (lane >> 3)) << 4;  // pre-swizzled src col
  const int l3 = lane >> 3;
  const int tx = (t & 7) << 4;                    // read-side XOR (bytes)

  auto SToff = [&](int h, int j) -> int {
    int ii = w * 2 + j;
    return (ii < 8) ? (h * 64 + ii * 8) : (128 + h * 64 + (ii - 8) * 8);
  };
  auto STAGE_A = [&](int p, int T, int h) {
#pragma unroll
    for (int j = 0; j < 2; ++j) {
      int rb = SToff(h, j);
      GLDS(Ab + (size_t)(m0 + rb + l3) * rowK + (size_t)T * 128 + srcx,
           &SA0[p * 16384 + rb * 64]);
    }
  };
  auto STAGE_B = [&](int p, int T, int h) {
#pragma unroll
    for (int j = 0; j < 2; ++j) {
      int rb = SToff(h, j);
      GLDS(Bb + (size_t)(n0 + rb + l3) * rowK + (size_t)T * 128 + srcx,
           &SB0[p * 16384 + rb * 64]);
    }
  };
  auto LDA = [&](int p, int q, int fr, int kk) -> bf16x8 {
    int ar = wr * 128 + q * 32 + fr * 16 + t;
    const char* ptr = (const char*)&SA0[p * 16384] + ar * 128 + ((kk * 64 + 16 * g) ^ tx);
    return __builtin_bit_cast(bf16x8, *(const u16x8*)ptr);
  };
  auto LDB = [&](int p, int nf, int kk) -> bf16x8 {
    int br = wc * 64 + nf * 16 + t;
    const char* ptr = (const char*)&SB0[p * 16384] + br * 128 + ((kk * 64 + 16 * g) ^ tx);
    return __builtin_bit_cast(bf16x8, *(const u16x8*)ptr);
  };

  f32x4 acc[8][4];
#pragma unroll
  for (int i = 0; i < 8; ++i)
#pragma unroll
    for (int j = 0; j < 4; ++j) acc[i][j] = (f32x4){0.f, 0.f, 0.f, 0.f};
  bf16x8 bfr[4][2];
  bf16x8 afr[2][4];

  // prologue: T0 complete (8 loads) + T1.{A0,B0,B1} (6 loads)
  STAGE_A(0, 0, 0); STAGE_B(0, 0, 0); STAGE_A(0, 0, 1); STAGE_B(0, 0, 1);
  STAGE_A(1, 1, 0); STAGE_B(1, 1, 0); STAGE_B(1, 1, 1);
  VM6;                                            // T0 landed
  __builtin_amdgcn_s_barrier();

  const int NI = (K_len >> 7) - 1;
  for (int i = 0; i < NI; ++i) {
    const int T1 = 2 * i + 1, T2 = 2 * i + 2, T3 = 2 * i + 3;
    LOADB8(0); LOADA4(0, 0, 0);
    STAGE_A(1, T1, 1); LOADA4(0, 1, 1); MMA16(0, 0); BARX;
    STAGE_B(0, T2, 0); LOADA4(0, 2, 0); MMA16(1, 1); BARX;
    STAGE_B(0, T2, 1); LOADA4(0, 3, 1); MMA16(2, 0); BARX;
    STAGE_A(0, T2, 0); MMA16(3, 1); VM6; BARX;
    LOADB8(1); LOADA4(1, 0, 0);
    STAGE_A(0, T2, 1); LOADA4(1, 1, 1); MMA16(0, 0); BARX;
    STAGE_B(1, T3, 0); LOADA4(1, 2, 0); MMA16(1, 1); BARX;
    STAGE_A(1, T3, 0); LOADA4(1, 3, 1); MMA16(2, 0); BARX;
    STAGE_B(1, T3, 1); MMA16(3, 1); VM6; BARX;
  }
  {                                               // peeled final iteration
    const int TL_ = (K_len >> 6) - 1;
    LOADB8(0); LOADA4(0, 0, 0);
    STAGE_A(1, TL_, 1); LOADA4(0, 1, 1); MMA16(0, 0); BARX;
    LOADA4(0, 2, 0); MMA16(1, 1); BARX;
    LOADA4(0, 3, 1); MMA16(2, 0); BARX;
    MMA16(3, 1); VM0; BARX;
    LOADB8(1); LOADA4(1, 0, 0);
    LOADA4(1, 1, 1); MMA16(0, 0); BARX;
    LOADA4(1, 2, 0); MMA16(1, 1); BARX;
    LOADA4(1, 3, 1); MMA16(2, 0); BARX;
    MMA16(3, 1);
  }

  if constexpr (MODE == 0 || MODE == 2) {
    // fp32 C-write (row = 4*(lane>>4)+reg, col = lane&15)
    const int cstride = (MODE == 0) ? N : 2048;
    const int cbase   = (MODE == 0) ? n0 : (n0 - 4096);
#pragma unroll
    for (int fi = 0; fi < 8; ++fi)
#pragma unroll
      for (int nf = 0; nf < 4; ++nf)
#pragma unroll
        for (int r = 0; r < 4; ++r) {
          int row = m0 + wr * 128 + fi * 16 + 4 * g + r;
          int col = cbase + wc * 64 + nf * 16 + t;
          Cu[(size_t)row * cstride + col] = acc[fi][nf][r];
        }
  } else {
    // MODE 1: fused RoPE-Q epilogue (n0 < 4096 always)
    u16* TL = (u16*)LDSBUF;                       // [256][TLS]
    __syncthreads();                              // all LDS reads of K-loop done
#pragma unroll
    for (int fi = 0; fi < 8; ++fi)
#pragma unroll
      for (int nf = 0; nf < 4; ++nf)
#pragma unroll
        for (int r = 0; r < 4; ++r)
          TL[(wr * 128 + fi * 16 + 4 * g + r) * TLS + wc * 64 + nf * 16 + t] =
              f2bf(acc[fi][nf][r]);
    __syncthreads();

    const int j = lane;                           // 0..63 = pair index
    const float ifr = exp2f(-(float)j * L2_1E4_64);
#pragma unroll 1
    for (int it = 0; it < 64; ++it) {
      int combo = w * 64 + it;                    // 0..511
      int row = combo & 255;
      int hh = combo >> 8;                        // 0/1: head within tile
      int tok = m0 + row;
      int b = tok >> 11, s = tok & (Ssz - 1);
      float x1 = bf2f(TL[row * TLS + hh * 128 + j]);
      float x2 = bf2f(TL[row * TLS + hh * 128 + 64 + j]);
      float p = (float)pos[tok];
      float ang = p * ifr;
      float sn, cs;
      __sincosf(ang, &sn, &cs);
      float o1 = (x1 * cs - x2 * sn) * QSCALE;
      float o2 = (x2 * cs + x1 * sn) * QSCALE;
      int h = (n0 >> 7) + hh;
      u16* o = Qr + ((size_t)(b * Hsz + h) * Ssz + s) * Dsz;
      o[j] = f2bf(o1); o[j + 64] = f2bf(o2);
    }
  }
}

// --------- K-region: sum K-split partials + RoPE -> Kr[b][kvh][s][d] --------
__global__ __launch_bounds__(256) void k_ropeK2(const float* __restrict__ Cp,
                                                const int* __restrict__ pos,
                                                u16* __restrict__ Kr) {
  int idx = blockIdx.x * 256 + threadIdx.x;       // B*S*KV*64
  if (idx >= Bsz * Ssz * KVsz * 64) return;
  const size_t OFF2 = (size_t)4096 * 2048;
  int j = idx & 63;
  int kvh = (idx >> 6) & 7;
  int bs = idx >> 9;                              // 0..4095
  size_t p0 = (size_t)bs * 2048 + kvh * 128 + j;
  float x1 = Cp[p0] + Cp[p0 + OFF2];
  float x2 = Cp[p0 + 64] + Cp[p0 + 64 + OFF2];
  float p = (float)pos[bs];
  float ang = p * exp2f(-(float)j * L2_1E4_64);
  float sn, cs;
  __sincosf(ang, &sn, &cs);
  int b = bs >> 11, sidx = bs & (Ssz - 1);
  u16* o = Kr + ((size_t)(b * KVsz + kvh) * Ssz + sidx) * Dsz;
  o[j] = f2bf(x1 * cs - x2 * sn);
  o[j + 64] = f2bf(x2 * cs + x1 * sn);
}

// --------- V-region: sum partials + LDS transpose -> Vt[bk][d][s] -----------
__global__ __launch_bounds__(256) void k_vtrans2(const float* __restrict__ Cp,
                                                 u16* __restrict__ Vt) {
  __shared__ __align__(16) u16 Tl[64 * 72];
  const int tid = threadIdx.x;
  const int bk = blockIdx.y;                      // b*KV + kvh
  const int s0 = (blockIdx.x >> 1) * 64;
  const int d0 = (blockIdx.x & 1) * 64;
  const int b = bk >> 3, kvh = bk & 7;
  const size_t OFF2 = (size_t)4096 * 2048;
  const size_t base = (size_t)(b * Ssz + s0) * 2048 + 1024 + kvh * 128 + d0;
#pragma unroll
  for (int p = 0; p < 2; ++p) {
    int cid = p * 256 + tid;
    int r = cid >> 3, co = cid & 7;
    int chunk = co ^ ((r >> 3) & 7);
    const float* s1 = Cp + base + (size_t)r * 2048 + co * 8;
    u16x8 v;
#pragma unroll
    for (int e = 0; e < 8; ++e) v[e] = f2bf(s1[e] + s1[OFF2 + e]);
    *(u16x8*)((char*)Tl + r * 144 + chunk * 16) = v;
  }
  __syncthreads();
#pragma unroll
  for (int p = 0; p < 2; ++p) {
    int cid = p * 256 + tid;
    int dr = cid >> 3, c = cid & 7;
    u16x8 v;
#pragma unroll
    for (int j = 0; j < 8; ++j) {
      int s = 8 * c + j;
      v[j] = *(const u16*)((char*)Tl + s * 144 + (((dr >> 3) ^ c) * 16) + (dr & 7) * 2);
    }
    *(u16x8*)(Vt + ((size_t)bk * Dsz + d0 + dr) * Ssz + s0 + 8 * c) = v;
  }
}

// ---------------- flash attention: 8-wave swapped-QK^T 32x32 ----------------
// r12: causal-triangle FOLD — grid (4, B*H); block bx handles q-tiles (7-bx)
// then (bx) sequentially: total KV-tiles = (32-4bx)+(4bx+4) = 36, uniform for
// every block. 256 blocks = exactly 1/CU, one clean round, no straggler tail
// (r11 counters: Occupancy 12% vs 25% static = pairing/tail idle).
__global__ __launch_bounds__(512, 1) void k_attn(const u16* __restrict__ Qr,
                                                 const u16* __restrict__ Kr,
                                                 const u16* __restrict__ Vt,
                                                 u16* __restrict__ AO) {
  __shared__ __align__(16) u16 Kl[2][64 * 128];  // [k][d] swizzled
  __shared__ __align__(16) u16 Vl[2][128 * 64];  // [d][k] swizzled
  const int tid = threadIdx.x;
  const int w = tid >> 6, lane = tid & 63;
  const int q = lane & 31, hi = lane >> 5;
  const int bh = blockIdx.y;
  const int b = bh >> 5, h = bh & 31;
  const int kvh = h >> 2;                        // GQA: H/KV = 4
  const int bx = blockIdx.x;                     // 0..3

  // loop-invariant LDS read byte-offsets (statically indexed -> registers)
  const int xq = (q & 7) << 4;
  int koff[8][2], voff[4][4];
#pragma unroll
  for (int ds = 0; ds < 8; ++ds) {
    int c = (ds * 32 + hi * 16) ^ xq;
    koff[ds][0] = q * 256 + c;
    koff[ds][1] = (32 + q) * 256 + c;
  }
#pragma unroll
  for (int ks = 0; ks < 4; ++ks) {
    int c = (ks * 32 + hi * 16) ^ xq;
#pragma unroll
    for (int dt = 0; dt < 4; ++dt)
      voff[ks][dt] = (dt * 32 + q) * 128 + c;
  }

  const char* Kbase = (const char*)(Kr + (size_t)(b * KVsz + kvh) * Ssz * Dsz);
  const char* Vbase = (const char*)(Vt + (size_t)(b * KVsz + kvh) * Dsz * Ssz);

  auto STAGE = [&](int bu, int kt2) {
    const char* Kb = Kbase + (size_t)kt2 * (64 * 256);
    const char* Vb = Vbase + (size_t)kt2 * 128;   // 64 cols * 2B
#pragma unroll
    for (int j = 0; j < 2; ++j) {
      int flat = j * 512 + tid;
      int row = flat >> 4, colb = ((flat & 15) * 16) ^ ((row & 7) << 4);
      GLDS(Kb + (size_t)row * 256 + colb, (char*)&Kl[bu][0] + flat * 16);
    }
#pragma unroll
    for (int j = 0; j < 2; ++j) {
      int flat = j * 512 + tid;
      int row = flat >> 3, colb = ((flat & 7) * 16) ^ ((row & 7) << 4);
      GLDS(Vb + (size_t)row * (Ssz * 2) + colb, (char*)&Vl[bu][0] + flat * 16);
    }
  };

#pragma unroll 1
  for (int pass = 0; pass < 2; ++pass) {
    const int bxr = pass ? bx : (7 - bx);
    const int q0 = bxr * 256;
    const int qw = q0 + w * 32;
    const int ntiles = 4 * bxr + 4;              // always even
    const int qg = qw + q;

    const u16* Qb = Qr + ((size_t)bh * Ssz + qw + q) * Dsz + hi * 8;
    bf16x8 qf[8];
#pragma unroll
    for (int ds = 0; ds < 8; ++ds)
      qf[ds] = __builtin_bit_cast(bf16x8, *(const u16x8*)(Qb + ds * 16));

    f32x16 oacc[4];
#pragma unroll
    for (int dt = 0; dt < 4; ++dt)
#pragma unroll
      for (int r = 0; r < 16; ++r) oacc[dt][r] = 0.f;
    float mr = -1e30f, lr = 0.f;

    STAGE(0, 0);
    __syncthreads();

    auto TILE = [&](int bufc, int kt) {
      const int k0 = kt * 64;
      if (kt + 1 < ntiles) STAGE(bufc ^ 1, kt + 1);  // prefetch overlaps compute

      if (k0 <= qw + 31) {                           // wave participates
        const char* Kb = (const char*)&Kl[bufc][0];
        const char* Vb = (const char*)&Vl[bufc][0];
        f32x16 pa0, pa1;
#pragma unroll
        for (int r = 0; r < 16; ++r) { pa0[r] = 0.f; pa1[r] = 0.f; }
        __builtin_amdgcn_s_setprio(1);
#pragma unroll
        for (int ds = 0; ds < 8; ++ds) {
          bf16x8 kf0 = __builtin_bit_cast(bf16x8, *(const u16x8*)(Kb + koff[ds][0]));
          pa0 = __builtin_amdgcn_mfma_f32_32x32x16_bf16(kf0, qf[ds], pa0, 0, 0, 0);
          bf16x8 kf1 = __builtin_bit_cast(bf16x8, *(const u16x8*)(Kb + koff[ds][1]));
          pa1 = __builtin_amdgcn_mfma_f32_32x32x16_bf16(kf1, qf[ds], pa1, 0, 0, 0);
        }
        __builtin_amdgcn_s_setprio(0);

        if (k0 + 63 > qw) {                          // causal mask (tail tiles)
#pragma unroll
          for (int reg = 0; reg < 16; ++reg) {
            const int kb = (reg & 3) + 8 * (reg >> 2) + 4 * hi;
            if (k0 + kb > qg)      pa0[reg] = -1e30f;
            if (k0 + 32 + kb > qg) pa1[reg] = -1e30f;
          }
        }
        float tmx[16];
#pragma unroll
        for (int i = 0; i < 16; ++i) tmx[i] = fmaxf(pa0[i], pa1[i]);
#pragma unroll
        for (int s = 8; s > 0; s >>= 1)
#pragma unroll
          for (int i = 0; i < s; ++i) tmx[i] = fmaxf(tmx[i], tmx[i + s]);
        const float mx = fmaxf(tmx[0], __shfl_xor(tmx[0], 32, 64));
        if (!__all(mx <= mr + 4.0f)) {               // T13 defer-max
          const float mnew = fmaxf(mr, mx);
          const float corr = exp2f(mr - mnew);
          lr *= corr;
#pragma unroll
          for (int dt = 0; dt < 4; ++dt)
#pragma unroll
            for (int reg = 0; reg < 16; ++reg) oacc[dt][reg] *= corr;
          mr = mnew;
        }
        float su[16];
#pragma unroll
        for (int reg = 0; reg < 16; ++reg) {
          pa0[reg] = exp2f(pa0[reg] - mr);
          pa1[reg] = exp2f(pa1[reg] - mr);
          su[reg] = pa0[reg] + pa1[reg];
        }
#pragma unroll
        for (int s = 8; s > 0; s >>= 1)
#pragma unroll
          for (int i = 0; i < s; ++i) su[i] += su[i + s];
        lr += su[0] + __shfl_xor(su[0], 32, 64);

        uint32_t W0[4][2], W1[4][2];
#pragma unroll
        for (int r2 = 0; r2 < 4; ++r2)
#pragma unroll
          for (int c = 0; c < 2; ++c) {
            W0[r2][c] = packc(pa0[4 * r2 + 2 * c], pa0[4 * r2 + 2 * c + 1]);
            W1[r2][c] = packc(pa1[4 * r2 + 2 * c], pa1[4 * r2 + 2 * c + 1]);
          }

        __builtin_amdgcn_s_setprio(1);
#pragma unroll
        for (int ks = 0; ks < 4; ++ks) {
          const int T = ks >> 1, r2e = 2 * (ks & 1);
          uint32_t a0 = T ? W1[r2e][0]     : W0[r2e][0];
          uint32_t a1 = T ? W1[r2e][1]     : W0[r2e][1];
          uint32_t b0 = T ? W1[r2e + 1][0] : W0[r2e + 1][0];
          uint32_t b1 = T ? W1[r2e + 1][1] : W0[r2e + 1][1];
          asm("v_permlane32_swap_b32 %0, %1" : "+v"(a0), "+v"(b0));
          asm("v_permlane32_swap_b32 %0, %1" : "+v"(a1), "+v"(b1));
          u32x4 fw; fw[0] = a0; fw[1] = a1; fw[2] = b0; fw[3] = b1;
          bf16x8 pf = __builtin_bit_cast(bf16x8, fw);
#pragma unroll
          for (int dt = 0; dt < 4; ++dt) {
            bf16x8 vf = __builtin_bit_cast(bf16x8, *(const u16x8*)(Vb + voff[ks][dt]));
            oacc[dt] = __builtin_amdgcn_mfma_f32_32x32x16_bf16(vf, pf, oacc[dt], 0, 0, 0);
          }
        }
        __builtin_amdgcn_s_setprio(0);
      }
      __syncthreads();                               // drains vmcnt: next buf ready
    };

    for (int kt = 0; kt < ntiles; kt += 2) {         // ntiles % 2 == 0 always
      TILE(0, kt);
      TILE(1, kt + 1);
    }

    const float inv = 1.f / lr;
    u16* Ob = AO + ((size_t)(b * Ssz) + qw + q) * HIDsz + h * Dsz + hi * 4;
#pragma unroll
    for (int dt = 0; dt < 4; ++dt)
#pragma unroll
      for (int r2 = 0; r2 < 4; ++r2) {
        u16x4 o4;
#pragma unroll
        for (int j = 0; j < 4; ++j) o4[j] = f2bf(oacc[dt][4 * r2 + j] * inv);
        *(u16x4*)(Ob + dt * 32 + r2 * 8) = o4;
      }
    // pass-1 epilogue touches only global memory; last TILE's barrier already
    // ordered all LDS reads before pass-2's STAGE overwrite -> no extra sync.
  }
}

// ---------------- host ----------------
extern "C" void kernel_launch(void* const* d_in, const int* in_sizes, int n_in,
                              void* d_out, int out_size, void* d_ws, size_t ws_size,
                              hipStream_t stream) {
  (void)in_sizes; (void)n_in; (void)out_size;
  const float* hs   = (const float*)d_in[0];
  const int*   pos  = (const int*)d_in[1];
  const float* Wqkv = (const float*)d_in[2];
  const float* Wo   = (const float*)d_in[3];

  char* ws = (char*)d_ws;
  const size_t SZ_XBF = (size_t)4096 * 4096 * 2;   // also reused for AO
  const size_t SZ_WQ  = (size_t)6144 * 4096 * 2;
  const size_t SZ_WO  = (size_t)4096 * 4096 * 2;
  const size_t SZ_QR  = (size_t)Bsz * Hsz * Ssz * Dsz * 2;
  const size_t SZ_KR  = (size_t)Bsz * KVsz * Ssz * Dsz * 2;
  const size_t SZ_VT  = SZ_KR;

  size_t off = 0;
  u16*   Xbf   = (u16*)(ws + off);  off += SZ_XBF;
  u16*   Wq_bf = (u16*)(ws + off);  off += SZ_WQ;
  u16*   Wo_bf = (u16*)(ws + off);  off += SZ_WO;
  u16*   Qr    = (u16*)(ws + off);  off += SZ_QR;
  u16*   Kr    = (u16*)(ws + off);  off += SZ_KR;
  u16*   Vt    = (u16*)(ws + off);  off += SZ_VT;
  u16*   AO    = Xbf;                               // alias (Xbf dead after gemm1)
  float* Cp    = (float*)d_out;                     // K-split partials: d_out as
                                                    // scratch, fully overwritten
                                                    // by gemm2 afterwards
  if (ws_size < off) return;                        // fail loudly

  // 1. fp32 -> bf16 conversions (single launch)
  k_cvt3<<<(N4_HS + N4_WQ + N4_WO + 255) / 256, 256, 0, stream>>>(
      hs, Wqkv, Wo, Xbf, Wq_bf, Wo_bf);

  // 2a. QKV projection, Q region (256 blocks, 1 clean round) + RoPE-Q -> Qr
  k_gemm256<1><<<256, 512, 0, stream>>>(Xbf, Wq_bf, nullptr, pos, Qr,
                                        Bsz * Ssz, NQKV, HIDsz, HIDsz);

  // 2b. K/V region K-split partials (256 blocks, 1 clean half-round) -> Cp
  k_gemm256<2><<<256, 512, 0, stream>>>(Xbf, Wq_bf, Cp, nullptr, nullptr,
                                        Bsz * Ssz, NQKV, HIDsz, 2048);

  // 2c. sum partials + RoPE-K -> Kr ; sum + transpose -> Vt
  k_ropeK2<<<(Bsz * Ssz * KVsz * 64) / 256, 256, 0, stream>>>(Cp, pos, Kr);
  k_vtrans2<<<dim3(64, Bsz * KVsz), 256, 0, stream>>>(Cp, Vt);

  // 3. causal GQA attention (folded-triangle uniform blocks) -> AO
  k_attn<<<dim3(4, Bsz * Hsz), 512, 0, stream>>>(Qr, Kr, Vt, AO);

  // 4. o_proj: [4096,4096] x [4096,4096]^T -> d_out fp32 (overwrites scratch)
  k_gemm256<0><<<256, 512, 0, stream>>>(AO, Wo_bf, (float*)d_out, nullptr,
                                        nullptr, Bsz * Ssz, HIDsz, HIDsz, HIDsz);
}

// Round 13
// 459.589 us; speedup vs baseline: 1.4780x; 1.0099x over previous
//
#include <hip/hip_runtime.h>
#include <stdint.h>
#include <stddef.h>

#define Bsz   2
#define Ssz   2048
#define HIDsz 4096
#define Hsz   32
#define KVsz  8
#define Dsz   128
#define NQKV  6144                     // (H+2KV)*D
// Q scale = 1/sqrt(128) * log2(e): softmax computed base-2 (exp2 is the HW op)
#define QSCALE 0.12752057463f
#define L2_1E4_64 0.20762050595f       // log2(10000)/64

typedef __bf16 bf16x8 __attribute__((ext_vector_type(8)));
typedef __bf16 bf16x2 __attribute__((ext_vector_type(2)));
typedef float  f32x4  __attribute__((ext_vector_type(4)));
typedef float  f32x16 __attribute__((ext_vector_type(16)));
typedef unsigned short u16;
typedef u16 u16x4 __attribute__((ext_vector_type(4)));
typedef u16 u16x8 __attribute__((ext_vector_type(8)));
typedef uint32_t u32x4 __attribute__((ext_vector_type(4)));

__device__ __forceinline__ u16 f2bf(float f) {
  uint32_t u = __builtin_bit_cast(uint32_t, f);
  u = (u + 0x7FFFu + ((u >> 16) & 1u)) >> 16;   // RNE
  return (u16)u;
}
__device__ __forceinline__ float bf2f(u16 h) {
  return __builtin_bit_cast(float, (uint32_t)h << 16);
}
// pair pack via compiler (emits v_cvt_pk_bf16_f32)
__device__ __forceinline__ uint32_t packc(float lo, float hi_) {
  bf16x2 t;
  t[0] = (__bf16)lo; t[1] = (__bf16)hi_;
  return __builtin_bit_cast(uint32_t, t);
}

// global -> LDS async copy, 16B per lane; LDS dest = wave-uniform base + lane*16
#define GLDS(gp, lp) __builtin_amdgcn_global_load_lds( \
    (__attribute__((address_space(1))) void*)(void*)(gp), \
    (__attribute__((address_space(3))) void*)(lp), 16, 0, 0)

// ---------------- fused fp32->bf16 conversion (one launch, 3 tensors) -------
#define N4_HS  ((Bsz * Ssz * HIDsz) / 4)
#define N4_WQ  ((NQKV * HIDsz) / 4)
#define N4_WO  ((HIDsz * HIDsz) / 4)
__global__ __launch_bounds__(256) void k_cvt3(const float* __restrict__ hs,
                                              const float* __restrict__ wqkv,
                                              const float* __restrict__ wo,
                                              u16* __restrict__ xbf,
                                              u16* __restrict__ wqbf,
                                              u16* __restrict__ wobf) {
  int i = blockIdx.x * 256 + threadIdx.x;
  const float* src; u16* dst; int off;
  if (i < N4_HS)                   { src = hs;   dst = xbf;  off = i; }
  else if (i < N4_HS + N4_WQ)      { src = wqkv; dst = wqbf; off = i - N4_HS; }
  else if (i < N4_HS + N4_WQ + N4_WO) { src = wo; dst = wobf; off = i - N4_HS - N4_WQ; }
  else return;
  float4 v = ((const float4*)src)[off];
  u16x4 o;
  o.x = f2bf(v.x); o.y = f2bf(v.y); o.z = f2bf(v.z); o.w = f2bf(v.w);
  ((u16x4*)dst)[off] = o;
}

// ============ 256x256 8-phase GEMM: C[M][N] = A[M][K] * B[N][K]^T ============
// MODE 0: plain fp32 C-write (o_proj), grid M/256 x N/256, stride N.
// MODE 1: Q-region of qkv-proj (bn 0..15, 256 blocks): fused RoPE-Q epilogue.
// MODE 2: K/V-region K-split partials: 128 tiles (bn 16..23) x 2 K-halves.

#define BARX do { asm volatile("" ::: "memory"); __builtin_amdgcn_s_barrier(); \
                  asm volatile("" ::: "memory"); } while (0)
#define VM6  asm volatile("s_waitcnt vmcnt(6)" ::: "memory")
#define VM0  asm volatile("s_waitcnt vmcnt(0)" ::: "memory")

#define LOADA4(P_, Q_, F_) do {                                               \
    afr[F_][0] = LDA(P_, Q_, 0, 0); afr[F_][1] = LDA(P_, Q_, 0, 1);           \
    afr[F_][2] = LDA(P_, Q_, 1, 0); afr[F_][3] = LDA(P_, Q_, 1, 1);           \
  } while (0)

#define LOADB8(P_) do {                                                       \
    _Pragma("unroll") for (int nf = 0; nf < 4; ++nf) {                        \
      bfr[nf][0] = LDB(P_, nf, 0); bfr[nf][1] = LDB(P_, nf, 1); }             \
  } while (0)

#define MMA16(Q_, F_) do {                                                    \
    __builtin_amdgcn_s_setprio(1);                                            \
    _Pragma("unroll") for (int nf = 0; nf < 4; ++nf) {                        \
      acc[(Q_)*2][nf]   = __builtin_amdgcn_mfma_f32_16x16x32_bf16(afr[F_][0], bfr[nf][0], acc[(Q_)*2][nf],   0,0,0); \
      acc[(Q_)*2+1][nf] = __builtin_amdgcn_mfma_f32_16x16x32_bf16(afr[F_][2], bfr[nf][0], acc[(Q_)*2+1][nf], 0,0,0); \
    }                                                                         \
    _Pragma("unroll") for (int nf = 0; nf < 4; ++nf) {                        \
      acc[(Q_)*2][nf]   = __builtin_amdgcn_mfma_f32_16x16x32_bf16(afr[F_][1], bfr[nf][1], acc[(Q_)*2][nf],   0,0,0); \
      acc[(Q_)*2+1][nf] = __builtin_amdgcn_mfma_f32_16x16x32_bf16(afr[F_][3], bfr[nf][1], acc[(Q_)*2+1][nf], 0,0,0); \
    }                                                                         \
    __builtin_amdgcn_s_setprio(0);                                            \
  } while (0)

#define TLS 258                         // MODE1 epilogue LDS tile stride (u16)

template <int MODE>
__global__ __launch_bounds__(512, 1) void k_gemm256(const u16* __restrict__ A,
                                                    const u16* __restrict__ Bm,
                                                    float* __restrict__ Cv,
                                                    const int* __restrict__ pos,
                                                    u16* __restrict__ Qr,
                                                    int M, int N, int K_ld,
                                                    int K_len) {
  constexpr int LDS_BYTES = (MODE == 1) ? (256 * TLS * 2) : (4 * 256 * 64 * 2);
  __shared__ __align__(16) char LDSBUF[LDS_BYTES];
  u16* SA0 = (u16*)LDSBUF;                        // SA[2][256*64]
  u16* SB0 = (u16*)(LDSBUF + 65536);              // SB[2][256*64]
  const int tid = threadIdx.x;
  const int w = tid >> 6, lane = tid & 63;
  const int g = lane >> 4, t = lane & 15;
  const int wr = w >> 2, wc = w & 3;
  const int cpx = gridDim.x >> 3;                 // grid %8 == 0 (always 256)
  const int swz = (blockIdx.x & 7) * cpx + (blockIdx.x >> 3);

  int bm, bn;
  const u16 *Au = A, *Bu = Bm;
  float* Cu = Cv;
  if constexpr (MODE == 2) {
    const int t2 = swz & 127, h2 = swz >> 7;
    bm = t2 & 15; bn = 16 + (t2 >> 4);
    Au = A + h2 * 2048; Bu = Bm + h2 * 2048;
    Cu = Cv + (size_t)h2 * 4096 * 2048;
  } else {
    const int MBt = M >> 8;
    bm = swz % MBt; bn = swz / MBt;               // column-major tile order
  }
  const int m0 = bm << 8, n0 = bn << 8;

  const char* Ab = (const char*)Au;
  const char* Bb = (const char*)Bu;
  const size_t rowK = (size_t)K_ld * 2;           // bytes per input row
  const int srcx = ((lane & 7) ^ (lane >> 3)) << 4;  // pre-swizzled src col
  const int l3 = lane >> 3;
  const int tx = (t & 7) << 4;                    // read-side XOR (bytes)

  auto SToff = [&](int h, int j) -> int {
    int ii = w * 2 + j;
    return (ii < 8) ? (h * 64 + ii * 8) : (128 + h * 64 + (ii - 8) * 8);
  };
  auto STAGE_A = [&](int p, int T, int h) {
#pragma unroll
    for (int j = 0; j < 2; ++j) {
      int rb = SToff(h, j);
      GLDS(Ab + (size_t)(m0 + rb + l3) * rowK + (size_t)T * 128 + srcx,
           &SA0[p * 16384 + rb * 64]);
    }
  };
  auto STAGE_B = [&](int p, int T, int h) {
#pragma unroll
    for (int j = 0; j < 2; ++j) {
      int rb = SToff(h, j);
      GLDS(Bb + (size_t)(n0 + rb + l3) * rowK + (size_t)T * 128 + srcx,
           &SB0[p * 16384 + rb * 64]);
    }
  };
  auto LDA = [&](int p, int q, int fr, int kk) -> bf16x8 {
    int ar = wr * 128 + q * 32 + fr * 16 + t;
    const char* ptr = (const char*)&SA0[p * 16384] + ar * 128 + ((kk * 64 + 16 * g) ^ tx);
    return __builtin_bit_cast(bf16x8, *(const u16x8*)ptr);
  };
  auto LDB = [&](int p, int nf, int kk) -> bf16x8 {
    int br = wc * 64 + nf * 16 + t;
    const char* ptr = (const char*)&SB0[p * 16384] + br * 128 + ((kk * 64 + 16 * g) ^ tx);
    return __builtin_bit_cast(bf16x8, *(const u16x8*)ptr);
  };

  f32x4 acc[8][4];
#pragma unroll
  for (int i = 0; i < 8; ++i)
#pragma unroll
    for (int j = 0; j < 4; ++j) acc[i][j] = (f32x4){0.f, 0.f, 0.f, 0.f};
  bf16x8 bfr[4][2];
  bf16x8 afr[2][4];

  // prologue: T0 complete (8 loads) + T1.{A0,B0,B1} (6 loads)
  STAGE_A(0, 0, 0); STAGE_B(0, 0, 0); STAGE_A(0, 0, 1); STAGE_B(0, 0, 1);
  STAGE_A(1, 1, 0); STAGE_B(1, 1, 0); STAGE_B(1, 1, 1);
  VM6;                                            // T0 landed
  __builtin_amdgcn_s_barrier();

  const int NI = (K_len >> 7) - 1;
  for (int i = 0; i < NI; ++i) {
    const int T1 = 2 * i + 1, T2 = 2 * i + 2, T3 = 2 * i + 3;
    LOADB8(0); LOADA4(0, 0, 0);
    STAGE_A(1, T1, 1); LOADA4(0, 1, 1); MMA16(0, 0); BARX;
    STAGE_B(0, T2, 0); LOADA4(0, 2, 0); MMA16(1, 1); BARX;
    STAGE_B(0, T2, 1); LOADA4(0, 3, 1); MMA16(2, 0); BARX;
    STAGE_A(0, T2, 0); MMA16(3, 1); VM6; BARX;
    LOADB8(1); LOADA4(1, 0, 0);
    STAGE_A(0, T2, 1); LOADA4(1, 1, 1); MMA16(0, 0); BARX;
    STAGE_B(1, T3, 0); LOADA4(1, 2, 0); MMA16(1, 1); BARX;
    STAGE_A(1, T3, 0); LOADA4(1, 3, 1); MMA16(2, 0); BARX;
    STAGE_B(1, T3, 1); MMA16(3, 1); VM6; BARX;
  }
  {                                               // peeled final iteration
    const int TL_ = (K_len >> 6) - 1;
    LOADB8(0); LOADA4(0, 0, 0);
    STAGE_A(1, TL_, 1); LOADA4(0, 1, 1); MMA16(0, 0); BARX;
    LOADA4(0, 2, 0); MMA16(1, 1); BARX;
    LOADA4(0, 3, 1); MMA16(2, 0); BARX;
    MMA16(3, 1); VM0; BARX;
    LOADB8(1); LOADA4(1, 0, 0);
    LOADA4(1, 1, 1); MMA16(0, 0); BARX;
    LOADA4(1, 2, 0); MMA16(1, 1); BARX;
    LOADA4(1, 3, 1); MMA16(2, 0); BARX;
    MMA16(3, 1);
  }

  if constexpr (MODE == 0 || MODE == 2) {
    // fp32 C-write (row = 4*(lane>>4)+reg, col = lane&15)
    const int cstride = (MODE == 0) ? N : 2048;
    const int cbase   = (MODE == 0) ? n0 : (n0 - 4096);
#pragma unroll
    for (int fi = 0; fi < 8; ++fi)
#pragma unroll
      for (int nf = 0; nf < 4; ++nf)
#pragma unroll
        for (int r = 0; r < 4; ++r) {
          int row = m0 + wr * 128 + fi * 16 + 4 * g + r;
          int col = cbase + wc * 64 + nf * 16 + t;
          Cu[(size_t)row * cstride + col] = acc[fi][nf][r];
        }
  } else {
    // MODE 1: fused RoPE-Q epilogue (n0 < 4096 always)
    u16* TL = (u16*)LDSBUF;                       // [256][TLS]
    __syncthreads();                              // all LDS reads of K-loop done
#pragma unroll
    for (int fi = 0; fi < 8; ++fi)
#pragma unroll
      for (int nf = 0; nf < 4; ++nf)
#pragma unroll
        for (int r = 0; r < 4; ++r)
          TL[(wr * 128 + fi * 16 + 4 * g + r) * TLS + wc * 64 + nf * 16 + t] =
              f2bf(acc[fi][nf][r]);
    __syncthreads();

    const int j = lane;                           // 0..63 = pair index
    const float ifr = exp2f(-(float)j * L2_1E4_64);
#pragma unroll 1
    for (int it = 0; it < 64; ++it) {
      int combo = w * 64 + it;                    // 0..511
      int row = combo & 255;
      int hh = combo >> 8;                        // 0/1: head within tile
      int tok = m0 + row;
      int b = tok >> 11, s = tok & (Ssz - 1);
      float x1 = bf2f(TL[row * TLS + hh * 128 + j]);
      float x2 = bf2f(TL[row * TLS + hh * 128 + 64 + j]);
      float p = (float)pos[tok];
      float ang = p * ifr;
      float sn, cs;
      __sincosf(ang, &sn, &cs);
      float o1 = (x1 * cs - x2 * sn) * QSCALE;
      float o2 = (x2 * cs + x1 * sn) * QSCALE;
      int h = (n0 >> 7) + hh;
      u16* o = Qr + ((size_t)(b * Hsz + h) * Ssz + s) * Dsz;
      o[j] = f2bf(o1); o[j + 64] = f2bf(o2);
    }
  }
}

// --------- K-region: sum K-split partials + RoPE -> Kr[b][kvh][s][d] --------
__global__ __launch_bounds__(256) void k_ropeK2(const float* __restrict__ Cp,
                                                const int* __restrict__ pos,
                                                u16* __restrict__ Kr) {
  int idx = blockIdx.x * 256 + threadIdx.x;       // B*S*KV*64
  if (idx >= Bsz * Ssz * KVsz * 64) return;
  const size_t OFF2 = (size_t)4096 * 2048;
  int j = idx & 63;
  int kvh = (idx >> 6) & 7;
  int bs = idx >> 9;                              // 0..4095
  size_t p0 = (size_t)bs * 2048 + kvh * 128 + j;
  float x1 = Cp[p0] + Cp[p0 + OFF2];
  float x2 = Cp[p0 + 64] + Cp[p0 + 64 + OFF2];
  float p = (float)pos[bs];
  float ang = p * exp2f(-(float)j * L2_1E4_64);
  float sn, cs;
  __sincosf(ang, &sn, &cs);
  int b = bs >> 11, sidx = bs & (Ssz - 1);
  u16* o = Kr + ((size_t)(b * KVsz + kvh) * Ssz + sidx) * Dsz;
  o[j] = f2bf(x1 * cs - x2 * sn);
  o[j + 64] = f2bf(x2 * cs + x1 * sn);
}

// --------- V-region: sum partials + LDS transpose -> Vt[bk][d][s] -----------
__global__ __launch_bounds__(256) void k_vtrans2(const float* __restrict__ Cp,
                                                 u16* __restrict__ Vt) {
  __shared__ __align__(16) u16 Tl[64 * 72];
  const int tid = threadIdx.x;
  const int bk = blockIdx.y;                      // b*KV + kvh
  const int s0 = (blockIdx.x >> 1) * 64;
  const int d0 = (blockIdx.x & 1) * 64;
  const int b = bk >> 3, kvh = bk & 7;
  const size_t OFF2 = (size_t)4096 * 2048;
  const size_t base = (size_t)(b * Ssz + s0) * 2048 + 1024 + kvh * 128 + d0;
#pragma unroll
  for (int p = 0; p < 2; ++p) {
    int cid = p * 256 + tid;
    int r = cid >> 3, co = cid & 7;
    int chunk = co ^ ((r >> 3) & 7);
    const float* s1 = Cp + base + (size_t)r * 2048 + co * 8;
    u16x8 v;
#pragma unroll
    for (int e = 0; e < 8; ++e) v[e] = f2bf(s1[e] + s1[OFF2 + e]);
    *(u16x8*)((char*)Tl + r * 144 + chunk * 16) = v;
  }
  __syncthreads();
#pragma unroll
  for (int p = 0; p < 2; ++p) {
    int cid = p * 256 + tid;
    int dr = cid >> 3, c = cid & 7;
    u16x8 v;
#pragma unroll
    for (int j = 0; j < 8; ++j) {
      int s = 8 * c + j;
      v[j] = *(const u16*)((char*)Tl + s * 144 + (((dr >> 3) ^ c) * 16) + (dr & 7) * 2);
    }
    *(u16x8*)(Vt + ((size_t)bk * Dsz + d0 + dr) * Ssz + s0 + 8 * c) = v;
  }
}

// ---------------- flash attention: 4-wave swapped-QK^T 32x32 ----------------
// r13: TLP over lockstep — 256-thread blocks (4 waves, 128 q-rows), 2 blocks/CU
// (LDS 64KB each). Two independent blocks per CU drift freely: one block's
// softmax VALU overlaps the other's MFMA (m114 co-scheduling). Triangle fold
// at 128-row granularity: block bx does q-tiles (15-bx) then (bx) ->
// (2(15-bx)+2) + (2bx+2) = 34 KV-tiles uniform. Grid (8, B*H) = 512 blocks.
// Extra KV re-reads land in L2 (r11: FETCH 53MB, KV is L2-resident).
__global__ __launch_bounds__(256, 2) void k_attn(const u16* __restrict__ Qr,
                                                 const u16* __restrict__ Kr,
                                                 const u16* __restrict__ Vt,
                                                 u16* __restrict__ AO) {
  __shared__ __align__(16) u16 Kl[2][64 * 128];  // [k][d] swizzled (32KB)
  __shared__ __align__(16) u16 Vl[2][128 * 64];  // [d][k] swizzled (32KB)
  const int tid = threadIdx.x;                   // 0..255
  const int w = tid >> 6, lane = tid & 63;       // w: 0..3
  const int q = lane & 31, hi = lane >> 5;
  const int bh = blockIdx.y;
  const int b = bh >> 5, h = bh & 31;
  const int kvh = h >> 2;                        // GQA: H/KV = 4
  const int bx = blockIdx.x;                     // 0..7

  // loop-invariant LDS read byte-offsets (statically indexed -> registers)
  const int xq = (q & 7) << 4;
  int koff[8][2], voff[4][4];
#pragma unroll
  for (int ds = 0; ds < 8; ++ds) {
    int c = (ds * 32 + hi * 16) ^ xq;
    koff[ds][0] = q * 256 + c;
    koff[ds][1] = (32 + q) * 256 + c;
  }
#pragma unroll
  for (int ks = 0; ks < 4; ++ks) {
    int c = (ks * 32 + hi * 16) ^ xq;
#pragma unroll
    for (int dt = 0; dt < 4; ++dt)
      voff[ks][dt] = (dt * 32 + q) * 128 + c;
  }

  const char* Kbase = (const char*)(Kr + (size_t)(b * KVsz + kvh) * Ssz * Dsz);
  const char* Vbase = (const char*)(Vt + (size_t)(b * KVsz + kvh) * Dsz * Ssz);

  auto STAGE = [&](int bu, int kt2) {            // 256 threads: 4+4 GLDS each
    const char* Kb = Kbase + (size_t)kt2 * (64 * 256);
    const char* Vb = Vbase + (size_t)kt2 * 128;   // 64 cols * 2B
#pragma unroll
    for (int j = 0; j < 4; ++j) {
      int flat = j * 256 + tid;
      int row = flat >> 4, colb = ((flat & 15) * 16) ^ ((row & 7) << 4);
      GLDS(Kb + (size_t)row * 256 + colb, (char*)&Kl[bu][0] + flat * 16);
    }
#pragma unroll
    for (int j = 0; j < 4; ++j) {
      int flat = j * 256 + tid;
      int row = flat >> 3, colb = ((flat & 7) * 16) ^ ((row & 7) << 4);
      GLDS(Vb + (size_t)row * (Ssz * 2) + colb, (char*)&Vl[bu][0] + flat * 16);
    }
  };

#pragma unroll 1
  for (int pass = 0; pass < 2; ++pass) {
    const int bxr = pass ? bx : (15 - bx);       // q-tile index (128 rows)
    const int q0 = bxr * 128;
    const int qw = q0 + w * 32;
    const int ntiles = 2 * bxr + 2;              // always even
    const int qg = qw + q;

    const u16* Qb = Qr + ((size_t)bh * Ssz + qw + q) * Dsz + hi * 8;
    bf16x8 qf[8];
#pragma unroll
    for (int ds = 0; ds < 8; ++ds)
      qf[ds] = __builtin_bit_cast(bf16x8, *(const u16x8*)(Qb + ds * 16));

    f32x16 oacc[4];
#pragma unroll
    for (int dt = 0; dt < 4; ++dt)
#pragma unroll
      for (int r = 0; r < 16; ++r) oacc[dt][r] = 0.f;
    float mr = -1e30f, lr = 0.f;

    STAGE(0, 0);
    __syncthreads();

    auto TILE = [&](int bufc, int kt) {
      const int k0 = kt * 64;
      if (kt + 1 < ntiles) STAGE(bufc ^ 1, kt + 1);  // prefetch overlaps compute

      if (k0 <= qw + 31) {                           // wave participates
        const char* Kb = (const char*)&Kl[bufc][0];
        const char* Vb = (const char*)&Vl[bufc][0];
        f32x16 pa0, pa1;
#pragma unroll
        for (int r = 0; r < 16; ++r) { pa0[r] = 0.f; pa1[r] = 0.f; }
        __builtin_amdgcn_s_setprio(1);
#pragma unroll
        for (int ds = 0; ds < 8; ++ds) {
          bf16x8 kf0 = __builtin_bit_cast(bf16x8, *(const u16x8*)(Kb + koff[ds][0]));
          pa0 = __builtin_amdgcn_mfma_f32_32x32x16_bf16(kf0, qf[ds], pa0, 0, 0, 0);
          bf16x8 kf1 = __builtin_bit_cast(bf16x8, *(const u16x8*)(Kb + koff[ds][1]));
          pa1 = __builtin_amdgcn_mfma_f32_32x32x16_bf16(kf1, qf[ds], pa1, 0, 0, 0);
        }
        __builtin_amdgcn_s_setprio(0);

        if (k0 + 63 > qw) {                          // causal mask (tail tiles)
#pragma unroll
          for (int reg = 0; reg < 16; ++reg) {
            const int kb = (reg & 3) + 8 * (reg >> 2) + 4 * hi;
            if (k0 + kb > qg)      pa0[reg] = -1e30f;
            if (k0 + 32 + kb > qg) pa1[reg] = -1e30f;
          }
        }
        float tmx[16];
#pragma unroll
        for (int i = 0; i < 16; ++i) tmx[i] = fmaxf(pa0[i], pa1[i]);
#pragma unroll
        for (int s = 8; s > 0; s >>= 1)
#pragma unroll
          for (int i = 0; i < s; ++i) tmx[i] = fmaxf(tmx[i], tmx[i + s]);
        const float mx = fmaxf(tmx[0], __shfl_xor(tmx[0], 32, 64));
        if (!__all(mx <= mr + 4.0f)) {               // T13 defer-max
          const float mnew = fmaxf(mr, mx);
          const float corr = exp2f(mr - mnew);
          lr *= corr;
#pragma unroll
          for (int dt = 0; dt < 4; ++dt)
#pragma unroll
            for (int reg = 0; reg < 16; ++reg) oacc[dt][reg] *= corr;
          mr = mnew;
        }
        float su[16];
#pragma unroll
        for (int reg = 0; reg < 16; ++reg) {
          pa0[reg] = exp2f(pa0[reg] - mr);
          pa1[reg] = exp2f(pa1[reg] - mr);
          su[reg] = pa0[reg] + pa1[reg];
        }
#pragma unroll
        for (int s = 8; s > 0; s >>= 1)
#pragma unroll
          for (int i = 0; i < s; ++i) su[i] += su[i + s];
        lr += su[0] + __shfl_xor(su[0], 32, 64);

        uint32_t W0[4][2], W1[4][2];
#pragma unroll
        for (int r2 = 0; r2 < 4; ++r2)
#pragma unroll
          for (int c = 0; c < 2; ++c) {
            W0[r2][c] = packc(pa0[4 * r2 + 2 * c], pa0[4 * r2 + 2 * c + 1]);
            W1[r2][c] = packc(pa1[4 * r2 + 2 * c], pa1[4 * r2 + 2 * c + 1]);
          }

        __builtin_amdgcn_s_setprio(1);
#pragma unroll
        for (int ks = 0; ks < 4; ++ks) {
          const int T = ks >> 1, r2e = 2 * (ks & 1);
          uint32_t a0 = T ? W1[r2e][0]     : W0[r2e][0];
          uint32_t a1 = T ? W1[r2e][1]     : W0[r2e][1];
          uint32_t b0 = T ? W1[r2e + 1][0] : W0[r2e + 1][0];
          uint32_t b1 = T ? W1[r2e + 1][1] : W0[r2e + 1][1];
          asm("v_permlane32_swap_b32 %0, %1" : "+v"(a0), "+v"(b0));
          asm("v_permlane32_swap_b32 %0, %1" : "+v"(a1), "+v"(b1));
          u32x4 fw; fw[0] = a0; fw[1] = a1; fw[2] = b0; fw[3] = b1;
          bf16x8 pf = __builtin_bit_cast(bf16x8, fw);
#pragma unroll
          for (int dt = 0; dt < 4; ++dt) {
            bf16x8 vf = __builtin_bit_cast(bf16x8, *(const u16x8*)(Vb + voff[ks][dt]));
            oacc[dt] = __builtin_amdgcn_mfma_f32_32x32x16_bf16(vf, pf, oacc[dt], 0, 0, 0);
          }
        }
        __builtin_amdgcn_s_setprio(0);
      }
      __syncthreads();                               // drains vmcnt: next buf ready
    };

    for (int kt = 0; kt < ntiles; kt += 2) {         // ntiles % 2 == 0 always
      TILE(0, kt);
      TILE(1, kt + 1);
    }

    const float inv = 1.f / lr;
    u16* Ob = AO + ((size_t)(b * Ssz) + qw + q) * HIDsz + h * Dsz + hi * 4;
#pragma unroll
    for (int dt = 0; dt < 4; ++dt)
#pragma unroll
      for (int r2 = 0; r2 < 4; ++r2) {
        u16x4 o4;
#pragma unroll
        for (int j = 0; j < 4; ++j) o4[j] = f2bf(oacc[dt][4 * r2 + j] * inv);
        *(u16x4*)(Ob + dt * 32 + r2 * 8) = o4;
      }
    // pass-1 epilogue touches only global memory; last TILE's barrier already
    // ordered all LDS reads before pass-2's STAGE overwrite -> no extra sync.
  }
}

// ---------------- host ----------------
extern "C" void kernel_launch(void* const* d_in, const int* in_sizes, int n_in,
                              void* d_out, int out_size, void* d_ws, size_t ws_size,
                              hipStream_t stream) {
  (void)in_sizes; (void)n_in; (void)out_size;
  const float* hs   = (const float*)d_in[0];
  const int*   pos  = (const int*)d_in[1];
  const float* Wqkv = (const float*)d_in[2];
  const float* Wo   = (const float*)d_in[3];

  char* ws = (char*)d_ws;
  const size_t SZ_XBF = (size_t)4096 * 4096 * 2;   // also reused for AO
  const size_t SZ_WQ  = (size_t)6144 * 4096 * 2;
  const size_t SZ_WO  = (size_t)4096 * 4096 * 2;
  const size_t SZ_QR  = (size_t)Bsz * Hsz * Ssz * Dsz * 2;
  const size_t SZ_KR  = (size_t)Bsz * KVsz * Ssz * Dsz * 2;
  const size_t SZ_VT  = SZ_KR;

  size_t off = 0;
  u16*   Xbf   = (u16*)(ws + off);  off += SZ_XBF;
  u16*   Wq_bf = (u16*)(ws + off);  off += SZ_WQ;
  u16*   Wo_bf = (u16*)(ws + off);  off += SZ_WO;
  u16*   Qr    = (u16*)(ws + off);  off += SZ_QR;
  u16*   Kr    = (u16*)(ws + off);  off += SZ_KR;
  u16*   Vt    = (u16*)(ws + off);  off += SZ_VT;
  u16*   AO    = Xbf;                               // alias (Xbf dead after gemm1)
  float* Cp    = (float*)d_out;                     // K-split partials: d_out as
                                                    // scratch, fully overwritten
                                                    // by gemm2 afterwards
  if (ws_size < off) return;                        // fail loudly

  // 1. fp32 -> bf16 conversions (single launch)
  k_cvt3<<<(N4_HS + N4_WQ + N4_WO + 255) / 256, 256, 0, stream>>>(
      hs, Wqkv, Wo, Xbf, Wq_bf, Wo_bf);

  // 2a. QKV projection, Q region (256 blocks, 1 clean round) + RoPE-Q -> Qr
  k_gemm256<1><<<256, 512, 0, stream>>>(Xbf, Wq_bf, nullptr, pos, Qr,
                                        Bsz * Ssz, NQKV, HIDsz, HIDsz);

  // 2b. K/V region K-split partials (256 blocks, 1 clean half-round) -> Cp
  k_gemm256<2><<<256, 512, 0, stream>>>(Xbf, Wq_bf, Cp, nullptr, nullptr,
                                        Bsz * Ssz, NQKV, HIDsz, 2048);

  // 2c. sum partials + RoPE-K -> Kr ; sum + transpose -> Vt
  k_ropeK2<<<(Bsz * Ssz * KVsz * 64) / 256, 256, 0, stream>>>(Cp, pos, Kr);
  k_vtrans2<<<dim3(64, Bsz * KVsz), 256, 0, stream>>>(Cp, Vt);

  // 3. causal GQA attention (folded triangle, 2 blocks/CU TLP) -> AO
  k_attn<<<dim3(8, Bsz * Hsz), 256, 0, stream>>>(Qr, Kr, Vt, AO);

  // 4. o_proj: [4096,4096] x [4096,4096]^T -> d_out fp32 (overwrites scratch)
  k_gemm256<0><<<256, 512, 0, stream>>>(AO, Wo_bf, (float*)d_out, nullptr,
                                        nullptr, Bsz * Ssz, HIDsz, HIDsz, HIDsz);
}